// Round 1
// 1842.094 us; speedup vs baseline: 2.2186x; 2.2186x over previous
//
#include <hip/hip_runtime.h>
#include <hip/hip_bf16.h>
#include <math.h>

#define BB 8
#define CC 256
#define HH 128
#define WW 128
#define HWSZ (HH*WW)              // 16384
#define NTOT ((size_t)BB*CC*HWSZ) // 33554432 elements

typedef __hip_bfloat16 bf16;
typedef __attribute__((ext_vector_type(8))) short short8v; // 8 bf16 = 4 VGPR (MFMA A/B frag)
typedef __attribute__((ext_vector_type(4))) float f32x4;   // MFMA C/D frag

__device__ __forceinline__ float ldf(const float* p) { return *p; }
__device__ __forceinline__ float ldf(const bf16* p) { return __bfloat162float(*p); }
__device__ __forceinline__ void stf(float* p, float v) { *p = v; }
__device__ __forceinline__ void stf(bf16* p, float v) { *p = __float2bfloat16(v); }

union bfu { bf16 b; unsigned short u; };
__device__ __forceinline__ unsigned short f2bf_bits(float v) { bfu c; c.b = __float2bfloat16(v); return c.u; }
__device__ __forceinline__ float bfbits2f(unsigned short u) { bfu c; c.u = u; return __bfloat162float(c.b); }

// ---------------------------------------------------------------- pool 3x3
__global__ __launch_bounds__(256) void pool3_kernel(const float* __restrict__ x,
                                                    bf16* __restrict__ yavg,
                                                    bf16* __restrict__ ymax) {
    size_t idx = (size_t)blockIdx.x * 256 + threadIdx.x; // over NTOT
    int w = idx & (WW - 1);
    int h = (idx >> 7) & (HH - 1);
    size_t bc = idx >> 14;
    const float* base = x + bc * HWSZ;
    float s = 0.f, mx = -INFINITY;
#pragma unroll
    for (int dy = -1; dy <= 1; ++dy) {
        int hh = h + dy; if (hh < 0 || hh >= HH) continue;
#pragma unroll
        for (int dx = -1; dx <= 1; ++dx) {
            int ww = w + dx; if (ww < 0 || ww >= WW) continue;
            float v = base[hh * WW + ww];
            s += v; mx = fmaxf(mx, v);
        }
    }
    stf(&yavg[idx], s * (1.f / 9.f)); // count_include_pad=True -> always /9
    stf(&ymax[idx], mx);              // zero-pad excluded from max (-inf)
}

// ---------------------------------------------------------------- conv1x1 MFMA GEMM
// Orientation: D[pixel][ochan] = X^T[pixel][k] * W^T[k][ochan]  (per batch).
// MFMA v_mfma_f32_16x16x32_bf16.  A-frag: lane l holds A[m=l&15][k=4*(l>>4)+(j&3)+16*(j>>2)];
// B symmetric; D: col=lane&15 (=o), row=4*(lane>>4)+reg (=pixel)  [measured m89/m91].
// LDS stores each 32-k chunk PERMUTED so a lane's 8 frag elems are one contiguous b128:
//   pos(kloc) = ((kloc>>2)&3)*8 + (kloc>>4)*4 + (kloc&3)
// Weights are split bf16 hi+lo (W = hi + lo) to keep fp32-weight accuracy.
#define EPI_NONE   0
#define EPI_RELU   1
#define EPI_ADDAUX 2
#define EPI_SIGMUL 3

#define BMP 128   // pixels per block tile (M)
#define BNO 128   // out-chans per block tile (N)
#define BKC 64    // k per LDS stage
#define LDK 72    // padded k-row length (shorts); 144B rows, 16B-aligned, ~2-way banks

template<bool SC, class T>
__device__ __forceinline__ unsigned short ld_bits(const T* p, float s);
template<> __device__ __forceinline__ unsigned short ld_bits<false, bf16>(const bf16* p, float) {
    bfu c; c.b = *p; return c.u;
}
template<> __device__ __forceinline__ unsigned short ld_bits<true, bf16>(const bf16* p, float s) {
    return f2bf_bits(__bfloat162float(*p) * s);
}
template<> __device__ __forceinline__ unsigned short ld_bits<false, float>(const float* p, float) {
    return f2bf_bits(*p);
}
template<> __device__ __forceinline__ unsigned short ld_bits<true, float>(const float* p, float s) {
    return f2bf_bits(*p * s);
}

// stage X tile: 128 pixels x 64 k, k-permuted, bf16.  tid: xp = tid&127, k-half = (tid>>7)*32.
// global loads: lanes differ only in pixel -> 128B/256B contiguous per instruction.
template<bool SC, class T>
__device__ __forceinline__ void stage_X(short* __restrict__ Xs,
                                        const T* __restrict__ in,
                                        const float* __restrict__ scale,
                                        int b, int cbase, size_t pbase, int tid)
{
    const int xp  = tid & 127;
    const int xkh = (tid >> 7) * 32;
    const T* src = in + ((size_t)b * 256 + cbase + xkh) * HWSZ + pbase + xp;
    short* dst = Xs + xp * LDK + xkh;
#pragma unroll
    for (int ch = 0; ch < 2; ++ch) {
        unsigned short us[16];
#pragma unroll
        for (int g = 0; g < 4; ++g) {
#pragma unroll
            for (int r = 0; r < 4; ++r) {
                int kloc = ch * 16 + g * 4 + r;
                float sc = SC ? scale[b * 256 + cbase + xkh + kloc] : 1.f;
                us[g * 4 + r] = ld_bits<SC, T>(src + (size_t)kloc * HWSZ, sc);
            }
        }
#pragma unroll
        for (int g = 0; g < 4; ++g) {
            uint2 wv;
            wv.x = (unsigned)us[g * 4 + 0] | ((unsigned)us[g * 4 + 1] << 16);
            wv.y = (unsigned)us[g * 4 + 2] | ((unsigned)us[g * 4 + 3] << 16);
            *(uint2*)(dst + g * 8 + ch * 4) = wv;  // pos = g*8 + ch*4 + r
        }
    }
}

// stage W tile: 128 o x 64 k fp32 -> bf16 hi + lo, k-permuted. tid: o = tid>>1, k-half = (tid&1)*32.
__device__ __forceinline__ void stage_W(short* __restrict__ Wh, short* __restrict__ Wl,
                                        const float* __restrict__ Wm, int WS,
                                        int obase, int k0, int tid)
{
    const int wo  = tid >> 1;
    const int wkh = (tid & 1) * 32;
    const float* wrow = Wm + (size_t)(obase + wo) * WS + k0 + wkh;
    short* dh = Wh + wo * LDK + wkh;
    short* dl = Wl + wo * LDK + wkh;
#pragma unroll
    for (int ch = 0; ch < 2; ++ch) {
        unsigned short uh[16], ul[16];
#pragma unroll
        for (int g = 0; g < 4; ++g) {
#pragma unroll
            for (int r = 0; r < 4; ++r) {
                float v = wrow[ch * 16 + g * 4 + r];
                unsigned short hb = f2bf_bits(v);
                uh[g * 4 + r] = hb;
                ul[g * 4 + r] = f2bf_bits(v - bfbits2f(hb));
            }
        }
#pragma unroll
        for (int g = 0; g < 4; ++g) {
            uint2 a, c;
            a.x = (unsigned)uh[g*4+0] | ((unsigned)uh[g*4+1] << 16);
            a.y = (unsigned)uh[g*4+2] | ((unsigned)uh[g*4+3] << 16);
            c.x = (unsigned)ul[g*4+0] | ((unsigned)ul[g*4+1] << 16);
            c.y = (unsigned)ul[g*4+2] | ((unsigned)ul[g*4+3] << 16);
            *(uint2*)(dh + g * 8 + ch * 4) = a;
            *(uint2*)(dl + g * 8 + ch * 4) = c;
        }
    }
}

__device__ __forceinline__ void load4f(const bf16* p, float* v) {
    ushort4 u = *(const ushort4*)p;
    v[0] = bfbits2f(u.x); v[1] = bfbits2f(u.y); v[2] = bfbits2f(u.z); v[3] = bfbits2f(u.w);
}
__device__ __forceinline__ void load4f(const float* p, float* v) {
    float4 u = *(const float4*)p;
    v[0] = u.x; v[1] = u.y; v[2] = u.z; v[3] = u.w;
}
__device__ __forceinline__ void store4(bf16* p, const float* v) {
    uint2 u;
    u.x = (unsigned)f2bf_bits(v[0]) | ((unsigned)f2bf_bits(v[1]) << 16);
    u.y = (unsigned)f2bf_bits(v[2]) | ((unsigned)f2bf_bits(v[3]) << 16);
    *(uint2*)p = u;
}
__device__ __forceinline__ void store4(float* p, const float* v) {
    *(float4*)p = make_float4(v[0], v[1], v[2], v[3]);
}

template<int MODE, bool TWO_IN, bool HAS_SCALE, bool HAS_V,
         class TIN1, class TIN2, class TAUX, class TOUT>
__global__ __launch_bounds__(256) void conv1x1_kernel(
    TOUT* __restrict__ out,
    const TIN1* __restrict__ in1,
    const TIN2* __restrict__ in2,
    const float* __restrict__ Wm, int WS,
    const float* __restrict__ bias,
    const TAUX* __restrict__ aux,
    const float* __restrict__ scale,   // per (b, in-chan) gate
    const float* __restrict__ vvec,    // per (b, pixel) scalar (V column)
    const float* __restrict__ vw)      // = Wm + 512 (stride WS)
{
    const int K = TWO_IN ? 512 : 256;
    __shared__ __align__(16) short Xs[BMP * LDK];
    __shared__ __align__(16) short Wh[BNO * LDK];
    __shared__ __align__(16) short Wl[BNO * LDK];
    const int tid = threadIdx.x;
    const int b = blockIdx.z;
    const size_t p0 = (size_t)blockIdx.x * BMP;
    const int o0 = blockIdx.y * BNO;
    const int lane = tid & 63, wave = tid >> 6;
    const int wr = wave >> 1, wc = wave & 1;   // wave sub-tile: 64 px x 64 o
    const int lrow = lane & 15, lg = lane >> 4;

    f32x4 acc[4][4];
#pragma unroll
    for (int mi = 0; mi < 4; ++mi)
#pragma unroll
        for (int ni = 0; ni < 4; ++ni) acc[mi][ni] = (f32x4)(0.f);

    for (int kt = 0; kt < K / BKC; ++kt) {
        const int k0 = kt * BKC;
        stage_W(Wh, Wl, Wm, WS, o0, k0, tid);
        if (TWO_IN && k0 >= 256)
            stage_X<false, TIN2>(Xs, in2, nullptr, b, k0 - 256, p0, tid);
        else
            stage_X<HAS_SCALE, TIN1>(Xs, in1, scale, b, k0, p0, tid);
        __syncthreads();
#pragma unroll
        for (int kk = 0; kk < 2; ++kk) {
            short8v af[4], bh[4], bl[4];
#pragma unroll
            for (int mi = 0; mi < 4; ++mi)
                af[mi] = *(const short8v*)&Xs[(wr * 64 + mi * 16 + lrow) * LDK + kk * 32 + lg * 8];
#pragma unroll
            for (int ni = 0; ni < 4; ++ni) {
                bh[ni] = *(const short8v*)&Wh[(wc * 64 + ni * 16 + lrow) * LDK + kk * 32 + lg * 8];
                bl[ni] = *(const short8v*)&Wl[(wc * 64 + ni * 16 + lrow) * LDK + kk * 32 + lg * 8];
            }
#pragma unroll
            for (int mi = 0; mi < 4; ++mi)
#pragma unroll
                for (int ni = 0; ni < 4; ++ni)
                    acc[mi][ni] = __builtin_amdgcn_mfma_f32_16x16x32_bf16(af[mi], bh[ni], acc[mi][ni], 0, 0, 0);
#pragma unroll
            for (int mi = 0; mi < 4; ++mi)
#pragma unroll
                for (int ni = 0; ni < 4; ++ni)
                    acc[mi][ni] = __builtin_amdgcn_mfma_f32_16x16x32_bf16(af[mi], bl[ni], acc[mi][ni], 0, 0, 0);
        }
        __syncthreads();
    }

    // epilogue: lane holds, per (mi,ni) frag, 4 CONSECUTIVE pixels at fixed o
#pragma unroll
    for (int ni = 0; ni < 4; ++ni) {
        const int o = o0 + wc * 64 + ni * 16 + lrow;
        const float bs = bias[o];
        const float vwo = HAS_V ? vw[(size_t)o * WS] : 0.f;
#pragma unroll
        for (int mi = 0; mi < 4; ++mi) {
            const size_t p = p0 + wr * 64 + mi * 16 + lg * 4;
            const size_t oidx = ((size_t)b * CC + o) * HWSZ + p;
            float auxv[4];
            if (MODE == EPI_ADDAUX || MODE == EPI_SIGMUL) load4f(&aux[oidx], auxv);
            float vv[4];
            if (HAS_V) load4f(&vvec[(size_t)b * HWSZ + p], vv);
            float vals[4];
#pragma unroll
            for (int r = 0; r < 4; ++r) {
                float val = acc[mi][ni][r] + bs;
                if (HAS_V) val += vwo * vv[r];
                if (MODE == EPI_RELU)        val = fmaxf(val, 0.f);
                else if (MODE == EPI_ADDAUX) val += auxv[r];
                else if (MODE == EPI_SIGMUL) val = (1.f / (1.f + __expf(-val))) * auxv[r];
                vals[r] = val;
            }
            store4(&out[oidx], vals);
        }
    }
}

// ---------------------------------------------------------------- CA reduce
__global__ __launch_bounds__(256) void ca_reduce_kernel(const float* __restrict__ xc,
                                                        float* __restrict__ avgv,
                                                        float* __restrict__ maxv) {
    int bc = blockIdx.x; // 0..2047
    const float* base = xc + (size_t)bc * HWSZ;
    float s = 0.f, mx = -INFINITY;
    for (int i = threadIdx.x; i < HWSZ; i += 256) {
        float v = base[i]; s += v; mx = fmaxf(mx, v);
    }
    for (int off = 32; off; off >>= 1) {
        s += __shfl_down(s, off);
        mx = fmaxf(mx, __shfl_down(mx, off));
    }
    __shared__ float ss[4], sm[4];
    int wid = threadIdx.x >> 6, lane = threadIdx.x & 63;
    if (lane == 0) { ss[wid] = s; sm[wid] = mx; }
    __syncthreads();
    if (threadIdx.x == 0) {
        float S = ss[0] + ss[1] + ss[2] + ss[3];
        float M = fmaxf(fmaxf(sm[0], sm[1]), fmaxf(sm[2], sm[3]));
        avgv[bc] = S * (1.f / HWSZ);
        maxv[bc] = M;
    }
}

// ---------------------------------------------------------------- CA MLP (tiny)
__global__ __launch_bounds__(256) void ca_mlp_kernel(
    const float* __restrict__ avgv, const float* __restrict__ maxv,
    const float* __restrict__ aw1, const float* __restrict__ ab1,
    const float* __restrict__ aw2, const float* __restrict__ ab2,
    const float* __restrict__ mw1, const float* __restrict__ mb1,
    const float* __restrict__ mw2, const float* __restrict__ mb2,
    float* __restrict__ gate) {
    int b = blockIdx.x;
    __shared__ float av[256], mv[256], ha[16], hm[16];
    int t = threadIdx.x;
    av[t] = avgv[b * 256 + t];
    mv[t] = maxv[b * 256 + t];
    __syncthreads();
    if (t < 16) {
        float s = ab1[t];
        for (int i = 0; i < 256; ++i) s += aw1[t * 256 + i] * av[i];
        ha[t] = fmaxf(s, 0.f);
    } else if (t < 32) {
        int r = t - 16;
        float s = mb1[r];
        for (int i = 0; i < 256; ++i) s += mw1[r * 256 + i] * mv[i];
        hm[r] = fmaxf(s, 0.f);
    }
    __syncthreads();
    float ya = ab2[t], ym = mb2[t];
    for (int r = 0; r < 16; ++r) {
        ya += aw2[t * 16 + r] * ha[r];
        ym += mw2[t * 16 + r] * hm[r];
    }
    float g = ya + ym;
    gate[b * 256 + t] = 1.f / (1.f + __expf(-g));
}

// ---------------------------------------------------------------- attention logits+softmax
template<bool STORE_M>
__global__ __launch_bounds__(256) void attn_kernel(
    const bf16* __restrict__ Q, const bf16* __restrict__ S,
    bf16* __restrict__ Mout, float* __restrict__ m0out)
{
    int bh = blockIdx.x; int b = bh >> 7, h = bh & 127;
    const bf16* Qb = Q + (size_t)b * CC * HWSZ + h * WW;
    const bf16* Sb = S + (size_t)b * CC * HWSZ + h * WW;
    __shared__ float Qs[16][128];
    __shared__ float Ss[16][128];
    int tid = threadIdx.x;
    int tx = tid & 15, ty = tid >> 4;
    float acc[8][8] = {};
    int lk = tid >> 4;
    int li = (tid & 15) * 8;
    for (int c0 = 0; c0 < 256; c0 += 16) {
#pragma unroll
        for (int r = 0; r < 8; ++r) {
            Qs[lk][li + r] = ldf(&Qb[(size_t)(c0 + lk) * HWSZ + li + r]);
            Ss[lk][li + r] = ldf(&Sb[(size_t)(c0 + lk) * HWSZ + li + r]);
        }
        __syncthreads();
#pragma unroll
        for (int kk = 0; kk < 16; ++kk) {
            float qa[8], sb2[8];
#pragma unroll
            for (int r = 0; r < 8; ++r) qa[r] = Qs[kk][ty * 8 + r];
#pragma unroll
            for (int q = 0; q < 8; ++q) sb2[q] = Ss[kk][tx * 8 + q];
#pragma unroll
            for (int r = 0; r < 8; ++r)
#pragma unroll
                for (int q = 0; q < 8; ++q) acc[r][q] += qa[r] * sb2[q];
        }
        __syncthreads();
    }
#pragma unroll
    for (int r = 0; r < 8; ++r) {
        float mx = acc[r][0];
#pragma unroll
        for (int q = 1; q < 8; ++q) mx = fmaxf(mx, acc[r][q]);
        for (int m = 1; m < 16; m <<= 1) mx = fmaxf(mx, __shfl_xor(mx, m));
        float sm = 0.f;
#pragma unroll
        for (int q = 0; q < 8; ++q) { float e = __expf(acc[r][q] - mx); acc[r][q] = e; sm += e; }
        for (int m = 1; m < 16; m <<= 1) sm += __shfl_xor(sm, m);
        float inv = 1.f / sm;
#pragma unroll
        for (int q = 0; q < 8; ++q) acc[r][q] *= inv;
    }
    if (STORE_M) {
        bf16* Mb = Mout + (size_t)bh * WW * WW;
#pragma unroll
        for (int r = 0; r < 8; ++r) {
            int i = ty * 8 + r;
#pragma unroll
            for (int q = 0; q < 8; ++q) stf(&Mb[i * WW + tx * 8 + q], acc[r][q]);
        }
    } else {
        __shared__ float cs[16][128];
#pragma unroll
        for (int q = 0; q < 8; ++q) {
            float s = 0.f;
#pragma unroll
            for (int r = 0; r < 8; ++r) s += acc[r][q];
            cs[ty][tx * 8 + q] = s;
        }
        __syncthreads();
        if (tid < 128) {
            float s = 0.f;
#pragma unroll
            for (int g = 0; g < 16; ++g) s += cs[g][tid];
            m0out[(size_t)b * HWSZ + h * WW + tid] = (s > 0.1f) ? 0.f : 1.f;
        }
    }
}

// ---------------------------------------------------------------- attention apply
__global__ __launch_bounds__(256) void attn_apply_kernel(
    const bf16* __restrict__ Mbuf, const bf16* __restrict__ v3,
    bf16* __restrict__ outb)
{
    int bh = blockIdx.x; int b = bh >> 7, h = bh & 127;
    int ch0 = blockIdx.y * 128;
    const bf16* Mb = Mbuf + (size_t)bh * WW * WW;
    const bf16* Vb = v3 + ((size_t)b * CC + ch0) * HWSZ + h * WW;
    bf16* Ob = outb + ((size_t)b * CC + ch0) * HWSZ + h * WW;
    __shared__ float Ms[16][132]; // [jj][i]
    __shared__ float Vs[16][132]; // [jj][c]
    int tid = threadIdx.x;
    int tx = tid & 15, ty = tid >> 4;
    float acc[8][8] = {}; // [cc][ii]
    int lr = tid >> 1;
    int ljb = (tid & 1) * 8;
    for (int j0 = 0; j0 < 128; j0 += 16) {
#pragma unroll
        for (int r = 0; r < 8; ++r) {
            Ms[ljb + r][lr] = ldf(&Mb[lr * WW + j0 + ljb + r]);
            Vs[ljb + r][lr] = ldf(&Vb[(size_t)lr * HWSZ + j0 + ljb + r]);
        }
        __syncthreads();
#pragma unroll
        for (int jj = 0; jj < 16; ++jj) {
            float mv[8], vvv[8];
#pragma unroll
            for (int ii = 0; ii < 8; ++ii) mv[ii] = Ms[jj][tx * 8 + ii];
#pragma unroll
            for (int ccx = 0; ccx < 8; ++ccx) vvv[ccx] = Vs[jj][ty * 8 + ccx];
#pragma unroll
            for (int ccx = 0; ccx < 8; ++ccx)
#pragma unroll
                for (int ii = 0; ii < 8; ++ii) acc[ccx][ii] += vvv[ccx] * mv[ii];
        }
        __syncthreads();
    }
#pragma unroll
    for (int ccx = 0; ccx < 8; ++ccx) {
        int c = ty * 8 + ccx;
#pragma unroll
        for (int ii = 0; ii < 8; ++ii)
            stf(&Ob[(size_t)c * HWSZ + tx * 8 + ii], acc[ccx][ii]);
    }
}

// ---------------------------------------------------------------- morphology
__global__ void morph_kernel(const float* __restrict__ in, float* __restrict__ out,
                             int Hd, int Wd, int r, float thresh) {
    int idx = blockIdx.x * 256 + threadIdx.x;
    int tot = BB * Hd * Wd;
    if (idx >= tot) return;
    int x = idx % Wd; int y = (idx / Wd) % Hd; int b = idx / (Wd * Hd);
    const float* base = in + (size_t)b * Hd * Wd;
    float s = 0.f;
    for (int dy = -r; dy <= r; ++dy) {
        int yy = y + dy; if (yy < 0 || yy >= Hd) continue;
        for (int dx = -r; dx <= r; ++dx) {
            if (dx * dx + dy * dy > r * r) continue;
            int xx = x + dx; if (xx < 0 || xx >= Wd) continue;
            s += base[yy * Wd + xx];
        }
    }
    out[idx] = (s > thresh) ? 1.f : 0.f;
}

__global__ void pad3_kernel(const float* __restrict__ in, float* __restrict__ out) {
    int idx = blockIdx.x * 256 + threadIdx.x;
    int tot = BB * 134 * 134; if (idx >= tot) return;
    int x = idx % 134; int y = (idx / 134) % 134; int b = idx / (134 * 134);
    float v = 0.f;
    int xs = x - 3, ys = y - 3;
    if (xs >= 0 && xs < 128 && ys >= 0 && ys < 128)
        v = in[((size_t)b * 128 + ys) * 128 + xs];
    out[idx] = v;
}

__global__ void vfinal_kernel(const float* __restrict__ in, float* __restrict__ V) {
    int idx = blockIdx.x * 256 + threadIdx.x; // B*HWSZ
    if (idx >= BB * HWSZ) return;
    int x = idx & 127; int y = (idx >> 7) & 127; int b = idx >> 14;
    V[idx] = 1.f - in[((size_t)b * 134 + y + 3) * 134 + (x + 3)];
}

// ---------------------------------------------------------------- launch
extern "C" void kernel_launch(void* const* d_in, const int* in_sizes, int n_in,
                              void* d_out, int out_size, void* d_ws, size_t ws_size,
                              hipStream_t stream) {
    const float* x_p   = (const float*)d_in[0];
    const float* x_c   = (const float*)d_in[1];
    const float* pa_w1 = (const float*)d_in[2];
    const float* pa_b1 = (const float*)d_in[3];
    const float* pa_w2 = (const float*)d_in[4];
    const float* pa_b2 = (const float*)d_in[5];
    const float* pa_wc = (const float*)d_in[6];
    const float* pa_bc = (const float*)d_in[7];
    const float* ca_aw1 = (const float*)d_in[8];
    const float* ca_ab1 = (const float*)d_in[9];
    const float* ca_aw2 = (const float*)d_in[10];
    const float* ca_ab2 = (const float*)d_in[11];
    const float* ca_mw1 = (const float*)d_in[12];
    const float* ca_mb1 = (const float*)d_in[13];
    const float* ca_mw2 = (const float*)d_in[14];
    const float* ca_mb2 = (const float*)d_in[15];
    const float* b1_w  = (const float*)d_in[16];
    const float* b1_b  = (const float*)d_in[17];
    const float* b2_w  = (const float*)d_in[18];
    const float* b2_b  = (const float*)d_in[19];
    const float* b3_w  = (const float*)d_in[20];
    const float* b3_b  = (const float*)d_in[21];
    const float* fus_w = (const float*)d_in[22];
    const float* fus_b = (const float*)d_in[23];
    float* out = (float*)d_out;

    // ws layout (total ~129.6 MiB): two full bf16 buffers + small fp32 scratch
    char* wsb = (char*)d_ws;
    bf16* A  = (bf16*)wsb;                    // NTOT bf16 (64 MiB)
    bf16* Bb = (bf16*)(wsb + NTOT * 2);       // NTOT bf16 (64 MiB)
    float* smalls = (float*)(wsb + NTOT * 4);
    float* avgv = smalls;                     // 2048
    float* maxv = smalls + 2048;              // 2048
    float* gate = smalls + 4096;              // 2048
    float* mph0 = smalls + 6144;              // 143648
    float* mph1 = mph0 + 143648;              // 143648
    float* Vfin = mph1 + 143648;              // 131072
    // d_out doubles as two bf16 scratch buffers until the final fusion conv
    bf16* D1 = (bf16*)d_out;                  // NTOT bf16
    bf16* D2 = D1 + NTOT;                     // NTOT bf16
    bf16* Mbuf = D1;                          // 16.7M bf16 (32 MiB), lives in D1 later

    dim3 cgrid(HWSZ / BMP, CC / BNO, BB);     // (128, 2, 8)
    const int TPB = 256;

    // --- PALayer ---
    pool3_kernel<<<NTOT / 256, TPB, 0, stream>>>(x_p, A, Bb); // y1->A, y2->Bb
    conv1x1_kernel<EPI_RELU, false, false, false, bf16, bf16, bf16, bf16>
        <<<cgrid, TPB, 0, stream>>>(D1, A, nullptr, pa_w1, 256, pa_b1,
                                    nullptr, nullptr, nullptr, nullptr);          // z1->D1
    conv1x1_kernel<EPI_ADDAUX, false, false, false, bf16, bf16, bf16, bf16>
        <<<cgrid, TPB, 0, stream>>>(D2, D1, nullptr, pa_w2, 256, pa_b2,
                                    A, nullptr, nullptr, nullptr);                // u=conv(z1)+y1 ->D2
    conv1x1_kernel<EPI_RELU, false, false, false, bf16, bf16, bf16, bf16>
        <<<cgrid, TPB, 0, stream>>>(A, Bb, nullptr, pa_w1, 256, pa_b1,
                                    nullptr, nullptr, nullptr, nullptr);          // z2->A
    conv1x1_kernel<EPI_ADDAUX, false, false, false, bf16, bf16, bf16, bf16>
        <<<cgrid, TPB, 0, stream>>>(D1, A, nullptr, pa_w2, 256, pa_b2,
                                    Bb, nullptr, nullptr, nullptr);               // v=conv(z2)+y2 ->D1
    conv1x1_kernel<EPI_SIGMUL, true, false, false, bf16, bf16, float, bf16>
        <<<cgrid, TPB, 0, stream>>>(A, D2, D1, pa_wc, 512, pa_bc,
                                    x_p, nullptr, nullptr, nullptr);              // buffer_p->A

    // --- CALayer gate ---
    ca_reduce_kernel<<<BB * CC, TPB, 0, stream>>>(x_c, avgv, maxv);
    ca_mlp_kernel<<<BB, TPB, 0, stream>>>(avgv, maxv, ca_aw1, ca_ab1, ca_aw2, ca_ab2,
                                          ca_mw1, ca_mb1, ca_mw2, ca_mb2, gate);

    // --- Q/S projections (buffer_c = gate * x_c fused via per-channel scale) ---
    conv1x1_kernel<EPI_NONE, false, false, false, bf16, bf16, bf16, bf16>
        <<<cgrid, TPB, 0, stream>>>(Bb, A, nullptr, b1_w, 256, b1_b,
                                    nullptr, nullptr, nullptr, nullptr);          // Q1->Bb
    conv1x1_kernel<EPI_NONE, false, false, false, bf16, bf16, bf16, bf16>
        <<<cgrid, TPB, 0, stream>>>(D1, A, nullptr, b2_w, 256, b2_b,
                                    nullptr, nullptr, nullptr, nullptr);          // S2->D1
    conv1x1_kernel<EPI_NONE, false, true, false, float, float, float, bf16>
        <<<cgrid, TPB, 0, stream>>>(A, x_c, nullptr, b1_w, 256, b1_b,
                                    nullptr, gate, nullptr, nullptr);             // Q2->A
    conv1x1_kernel<EPI_NONE, false, true, false, float, float, float, bf16>
        <<<cgrid, TPB, 0, stream>>>(D2, x_c, nullptr, b2_w, 256, b2_b,
                                    nullptr, gate, nullptr, nullptr);             // S1->D2

    // --- attention softmaxes ---
    attn_kernel<false><<<BB * HH, TPB, 0, stream>>>(A, D1, nullptr, mph0);  // M_p_to_c colsum -> m0
    attn_kernel<true><<<BB * HH, TPB, 0, stream>>>(Bb, D2, Mbuf, nullptr);  // M_c_to_p -> Mbuf (D1)

    // --- v3 (independent of D1/D2 now) ---
    conv1x1_kernel<EPI_NONE, false, false, false, float, float, float, bf16>
        <<<cgrid, TPB, 0, stream>>>(A, x_c, nullptr, b3_w, 256, b3_b,
                                    nullptr, nullptr, nullptr, nullptr);          // v3->A

    // --- morphology (tiny) ---
    morph_kernel<<<512, TPB, 0, stream>>>(mph0, mph1, 128, 128, 2, 12.5f); // erode d2 (|d2|=13)
    morph_kernel<<<512, TPB, 0, stream>>>(mph1, mph0, 128, 128, 2, 0.5f);  // dilate d2
    morph_kernel<<<512, TPB, 0, stream>>>(mph0, mph1, 128, 128, 1, 0.5f);  // dilate d1
    morph_kernel<<<512, TPB, 0, stream>>>(mph1, mph0, 128, 128, 1, 4.5f);  // erode d1 (|d1|=5)
    pad3_kernel<<<562, TPB, 0, stream>>>(mph0, mph1);
    morph_kernel<<<562, TPB, 0, stream>>>(mph1, mph0, 134, 134, 3, 0.5f);  // dilate d3
    morph_kernel<<<562, TPB, 0, stream>>>(mph0, mph1, 134, 134, 3, 28.5f); // erode d3 (|d3|=29)
    vfinal_kernel<<<512, TPB, 0, stream>>>(mph1, Vfin);

    // --- attend + fusion ---
    attn_apply_kernel<<<dim3(BB * HH, 2), TPB, 0, stream>>>(Mbuf, A, Bb);  // bufA->Bb (over dead Q1)
    conv1x1_kernel<EPI_NONE, true, false, true, bf16, float, float, float>
        <<<cgrid, TPB, 0, stream>>>(out, Bb, x_p, fus_w, 513, fus_b,
                                    nullptr, nullptr, Vfin, fus_w + 512);         // final -> d_out fp32
}

// Round 2
// 1562.856 us; speedup vs baseline: 2.6151x; 1.1787x over previous
//
#include <hip/hip_runtime.h>
#include <hip/hip_bf16.h>
#include <math.h>

#define BB 8
#define CC 256
#define HH 128
#define WW 128
#define HWSZ (HH*WW)              // 16384
#define NTOT ((size_t)BB*CC*HWSZ) // 33554432 elements

typedef __hip_bfloat16 bf16;
typedef __attribute__((ext_vector_type(8))) short short8v; // 8 bf16 = 4 VGPR (MFMA A/B frag)
typedef __attribute__((ext_vector_type(4))) float f32x4;   // MFMA C/D frag

__device__ __forceinline__ float ldf(const float* p) { return *p; }
__device__ __forceinline__ float ldf(const bf16* p) { return __bfloat162float(*p); }
__device__ __forceinline__ void stf(float* p, float v) { *p = v; }
__device__ __forceinline__ void stf(bf16* p, float v) { *p = __float2bfloat16(v); }

union bfu { bf16 b; unsigned short u; };
__device__ __forceinline__ unsigned short f2bf_bits(float v) { bfu c; c.b = __float2bfloat16(v); return c.u; }
__device__ __forceinline__ float bfbits2f(unsigned short u) { bfu c; c.u = u; return __bfloat162float(c.b); }
__device__ __forceinline__ unsigned pk2(float a, float b) {
    return (unsigned)f2bf_bits(a) | ((unsigned)f2bf_bits(b) << 16);
}

// ---------------------------------------------------------------- pool 3x3
// 8 outputs per thread along w; separable horizontal window + vertical accumulate.
__global__ __launch_bounds__(256) void pool3_kernel(const float* __restrict__ x,
                                                    bf16* __restrict__ yavg,
                                                    bf16* __restrict__ ymax) {
    size_t idx = (size_t)blockIdx.x * 256 + threadIdx.x; // over NTOT/8
    int w0 = (int)(idx & 15) * 8;
    int h = (int)(idx >> 4) & 127;
    size_t bc = idx >> 11;
    const float* base = x + bc * HWSZ;
    float ts[8], tm[8];
#pragma unroll
    for (int i = 0; i < 8; ++i) { ts[i] = 0.f; tm[i] = -INFINITY; }
#pragma unroll
    for (int dy = -1; dy <= 1; ++dy) {
        int hh = h + dy;
        if (hh < 0 || hh >= HH) continue;
        const float* rp = base + hh * WW + w0;
        float4 v0 = *(const float4*)rp;
        float4 v1 = *(const float4*)(rp + 4);
        float s9[10], m9[10];
        s9[1] = v0.x; s9[2] = v0.y; s9[3] = v0.z; s9[4] = v0.w;
        s9[5] = v1.x; s9[6] = v1.y; s9[7] = v1.z; s9[8] = v1.w;
#pragma unroll
        for (int i = 1; i < 9; ++i) m9[i] = s9[i];
        if (w0 > 0)      { float L = rp[-1]; s9[0] = L; m9[0] = L; }
        else             { s9[0] = 0.f; m9[0] = -INFINITY; }
        if (w0 < WW - 8) { float R = rp[8]; s9[9] = R; m9[9] = R; }
        else             { s9[9] = 0.f; m9[9] = -INFINITY; }
#pragma unroll
        for (int i = 0; i < 8; ++i) {
            ts[i] += s9[i] + s9[i + 1] + s9[i + 2];
            tm[i] = fmaxf(tm[i], fmaxf(m9[i], fmaxf(m9[i + 1], m9[i + 2])));
        }
    }
    uint4 ua, um;
    ua.x = pk2(ts[0] * (1.f/9.f), ts[1] * (1.f/9.f));
    ua.y = pk2(ts[2] * (1.f/9.f), ts[3] * (1.f/9.f));
    ua.z = pk2(ts[4] * (1.f/9.f), ts[5] * (1.f/9.f));
    ua.w = pk2(ts[6] * (1.f/9.f), ts[7] * (1.f/9.f));
    um.x = pk2(tm[0], tm[1]); um.y = pk2(tm[2], tm[3]);
    um.z = pk2(tm[4], tm[5]); um.w = pk2(tm[6], tm[7]);
    *(uint4*)(yavg + idx * 8) = ua;
    *(uint4*)(ymax + idx * 8) = um;
}

// ---------------------------------------------------------------- conv1x1 MFMA GEMM
// (unchanged from round 1 — verified: k-permuted LDS frag layout, hi+lo weight split)
#define EPI_NONE   0
#define EPI_RELU   1
#define EPI_ADDAUX 2
#define EPI_SIGMUL 3

#define BMP 128   // pixels per block tile (M)
#define BNO 128   // out-chans per block tile (N)
#define BKC 64    // k per LDS stage
#define LDK 72    // padded k-row length (shorts)

template<bool SC, class T>
__device__ __forceinline__ unsigned short ld_bits(const T* p, float s);
template<> __device__ __forceinline__ unsigned short ld_bits<false, bf16>(const bf16* p, float) {
    bfu c; c.b = *p; return c.u;
}
template<> __device__ __forceinline__ unsigned short ld_bits<true, bf16>(const bf16* p, float s) {
    return f2bf_bits(__bfloat162float(*p) * s);
}
template<> __device__ __forceinline__ unsigned short ld_bits<false, float>(const float* p, float) {
    return f2bf_bits(*p);
}
template<> __device__ __forceinline__ unsigned short ld_bits<true, float>(const float* p, float s) {
    return f2bf_bits(*p * s);
}

// stage from column-major [k][x] (stride HWSZ) into k-permuted LDS rows
template<bool SC, class T>
__device__ __forceinline__ void stage_X(short* __restrict__ Xs,
                                        const T* __restrict__ in,
                                        const float* __restrict__ scale,
                                        int b, int cbase, size_t pbase, int tid)
{
    const int xp  = tid & 127;
    const int xkh = (tid >> 7) * 32;
    const T* src = in + ((size_t)b * 256 + cbase + xkh) * HWSZ + pbase + xp;
    short* dst = Xs + xp * LDK + xkh;
#pragma unroll
    for (int ch = 0; ch < 2; ++ch) {
        unsigned short us[16];
#pragma unroll
        for (int g = 0; g < 4; ++g) {
#pragma unroll
            for (int r = 0; r < 4; ++r) {
                int kloc = ch * 16 + g * 4 + r;
                float sc = SC ? scale[b * 256 + cbase + xkh + kloc] : 1.f;
                us[g * 4 + r] = ld_bits<SC, T>(src + (size_t)kloc * HWSZ, sc);
            }
        }
#pragma unroll
        for (int g = 0; g < 4; ++g) {
            uint2 wv;
            wv.x = (unsigned)us[g * 4 + 0] | ((unsigned)us[g * 4 + 1] << 16);
            wv.y = (unsigned)us[g * 4 + 2] | ((unsigned)us[g * 4 + 3] << 16);
            *(uint2*)(dst + g * 8 + ch * 4) = wv;  // pos = g*8 + ch*4 + r
        }
    }
}

// stage W tile fp32 -> bf16 hi+lo, k-permuted
__device__ __forceinline__ void stage_W(short* __restrict__ Wh, short* __restrict__ Wl,
                                        const float* __restrict__ Wm, int WS,
                                        int obase, int k0, int tid)
{
    const int wo  = tid >> 1;
    const int wkh = (tid & 1) * 32;
    const float* wrow = Wm + (size_t)(obase + wo) * WS + k0 + wkh;
    short* dh = Wh + wo * LDK + wkh;
    short* dl = Wl + wo * LDK + wkh;
#pragma unroll
    for (int ch = 0; ch < 2; ++ch) {
        unsigned short uh[16], ul[16];
#pragma unroll
        for (int g = 0; g < 4; ++g) {
#pragma unroll
            for (int r = 0; r < 4; ++r) {
                float v = wrow[ch * 16 + g * 4 + r];
                unsigned short hb = f2bf_bits(v);
                uh[g * 4 + r] = hb;
                ul[g * 4 + r] = f2bf_bits(v - bfbits2f(hb));
            }
        }
#pragma unroll
        for (int g = 0; g < 4; ++g) {
            uint2 a, c;
            a.x = (unsigned)uh[g*4+0] | ((unsigned)uh[g*4+1] << 16);
            a.y = (unsigned)uh[g*4+2] | ((unsigned)uh[g*4+3] << 16);
            c.x = (unsigned)ul[g*4+0] | ((unsigned)ul[g*4+1] << 16);
            c.y = (unsigned)ul[g*4+2] | ((unsigned)ul[g*4+3] << 16);
            *(uint2*)(dh + g * 8 + ch * 4) = a;
            *(uint2*)(dl + g * 8 + ch * 4) = c;
        }
    }
}

// stage from row-major (k-contiguous) source into k-permuted LDS rows
__device__ __forceinline__ void stage_rm(short* __restrict__ Xs, const bf16* __restrict__ src,
                                         size_t rstride, int k0, int tid)
{
    const int row = tid & 127;
    const int kh = (tid >> 7) * 32;
    const short* sp = (const short*)src + (size_t)row * rstride + k0 + kh;
    short* dst = Xs + row * LDK + kh;
#pragma unroll
    for (int q = 0; q < 4; ++q) {
        short8v v = *(const short8v*)(sp + q * 8);
        uint2 lo, hi;
        lo.x = (unsigned)(unsigned short)v[0] | ((unsigned)(unsigned short)v[1] << 16);
        lo.y = (unsigned)(unsigned short)v[2] | ((unsigned)(unsigned short)v[3] << 16);
        hi.x = (unsigned)(unsigned short)v[4] | ((unsigned)(unsigned short)v[5] << 16);
        hi.y = (unsigned)(unsigned short)v[6] | ((unsigned)(unsigned short)v[7] << 16);
        *(uint2*)(dst + ((2*q) & 3) * 8 + (q >> 1) * 4) = lo;
        *(uint2*)(dst + ((2*q+1) & 3) * 8 + (q >> 1) * 4) = hi;
    }
}

__device__ __forceinline__ void load4f(const bf16* p, float* v) {
    ushort4 u = *(const ushort4*)p;
    v[0] = bfbits2f(u.x); v[1] = bfbits2f(u.y); v[2] = bfbits2f(u.z); v[3] = bfbits2f(u.w);
}
__device__ __forceinline__ void load4f(const float* p, float* v) {
    float4 u = *(const float4*)p;
    v[0] = u.x; v[1] = u.y; v[2] = u.z; v[3] = u.w;
}
__device__ __forceinline__ void store4(bf16* p, const float* v) {
    uint2 u;
    u.x = pk2(v[0], v[1]);
    u.y = pk2(v[2], v[3]);
    *(uint2*)p = u;
}
__device__ __forceinline__ void store4(float* p, const float* v) {
    *(float4*)p = make_float4(v[0], v[1], v[2], v[3]);
}

template<int MODE, bool TWO_IN, bool HAS_SCALE, bool HAS_V,
         class TIN1, class TIN2, class TAUX, class TOUT>
__global__ __launch_bounds__(256) void conv1x1_kernel(
    TOUT* __restrict__ out,
    const TIN1* __restrict__ in1,
    const TIN2* __restrict__ in2,
    const float* __restrict__ Wm, int WS,
    const float* __restrict__ bias,
    const TAUX* __restrict__ aux,
    const float* __restrict__ scale,
    const float* __restrict__ vvec,
    const float* __restrict__ vw)
{
    const int K = TWO_IN ? 512 : 256;
    __shared__ __align__(16) short Xs[BMP * LDK];
    __shared__ __align__(16) short Wh[BNO * LDK];
    __shared__ __align__(16) short Wl[BNO * LDK];
    const int tid = threadIdx.x;
    const int b = blockIdx.z;
    const size_t p0 = (size_t)blockIdx.x * BMP;
    const int o0 = blockIdx.y * BNO;
    const int lane = tid & 63, wave = tid >> 6;
    const int wr = wave >> 1, wc = wave & 1;
    const int lrow = lane & 15, lg = lane >> 4;

    f32x4 acc[4][4];
#pragma unroll
    for (int mi = 0; mi < 4; ++mi)
#pragma unroll
        for (int ni = 0; ni < 4; ++ni) acc[mi][ni] = (f32x4)(0.f);

    for (int kt = 0; kt < K / BKC; ++kt) {
        const int k0 = kt * BKC;
        stage_W(Wh, Wl, Wm, WS, o0, k0, tid);
        if (TWO_IN && k0 >= 256)
            stage_X<false, TIN2>(Xs, in2, nullptr, b, k0 - 256, p0, tid);
        else
            stage_X<HAS_SCALE, TIN1>(Xs, in1, scale, b, k0, p0, tid);
        __syncthreads();
#pragma unroll
        for (int kk = 0; kk < 2; ++kk) {
            short8v af[4], bh[4], bl[4];
#pragma unroll
            for (int mi = 0; mi < 4; ++mi)
                af[mi] = *(const short8v*)&Xs[(wr * 64 + mi * 16 + lrow) * LDK + kk * 32 + lg * 8];
#pragma unroll
            for (int ni = 0; ni < 4; ++ni) {
                bh[ni] = *(const short8v*)&Wh[(wc * 64 + ni * 16 + lrow) * LDK + kk * 32 + lg * 8];
                bl[ni] = *(const short8v*)&Wl[(wc * 64 + ni * 16 + lrow) * LDK + kk * 32 + lg * 8];
            }
#pragma unroll
            for (int mi = 0; mi < 4; ++mi)
#pragma unroll
                for (int ni = 0; ni < 4; ++ni)
                    acc[mi][ni] = __builtin_amdgcn_mfma_f32_16x16x32_bf16(af[mi], bh[ni], acc[mi][ni], 0, 0, 0);
#pragma unroll
            for (int mi = 0; mi < 4; ++mi)
#pragma unroll
                for (int ni = 0; ni < 4; ++ni)
                    acc[mi][ni] = __builtin_amdgcn_mfma_f32_16x16x32_bf16(af[mi], bl[ni], acc[mi][ni], 0, 0, 0);
        }
        __syncthreads();
    }

#pragma unroll
    for (int ni = 0; ni < 4; ++ni) {
        const int o = o0 + wc * 64 + ni * 16 + lrow;
        const float bs = bias[o];
        const float vwo = HAS_V ? vw[(size_t)o * WS] : 0.f;
#pragma unroll
        for (int mi = 0; mi < 4; ++mi) {
            const size_t p = p0 + wr * 64 + mi * 16 + lg * 4;
            const size_t oidx = ((size_t)b * CC + o) * HWSZ + p;
            float auxv[4];
            if (MODE == EPI_ADDAUX || MODE == EPI_SIGMUL) load4f(&aux[oidx], auxv);
            float vv[4];
            if (HAS_V) load4f(&vvec[(size_t)b * HWSZ + p], vv);
            float vals[4];
#pragma unroll
            for (int r = 0; r < 4; ++r) {
                float val = acc[mi][ni][r] + bs;
                if (HAS_V) val += vwo * vv[r];
                if (MODE == EPI_RELU)        val = fmaxf(val, 0.f);
                else if (MODE == EPI_ADDAUX) val += auxv[r];
                else if (MODE == EPI_SIGMUL) val = (1.f / (1.f + __expf(-val))) * auxv[r];
                vals[r] = val;
            }
            store4(&out[oidx], vals);
        }
    }
}

// ---------------------------------------------------------------- CA reduce
__global__ __launch_bounds__(256) void ca_reduce_kernel(const float* __restrict__ xc,
                                                        float* __restrict__ avgv,
                                                        float* __restrict__ maxv) {
    int bc = blockIdx.x; // 0..2047
    const float4* base = (const float4*)(xc + (size_t)bc * HWSZ);
    float s = 0.f, mx = -INFINITY;
    for (int i = threadIdx.x; i < HWSZ / 4; i += 256) {
        float4 v = base[i];
        s += v.x + v.y + v.z + v.w;
        mx = fmaxf(mx, fmaxf(fmaxf(v.x, v.y), fmaxf(v.z, v.w)));
    }
    for (int off = 32; off; off >>= 1) {
        s += __shfl_down(s, off);
        mx = fmaxf(mx, __shfl_down(mx, off));
    }
    __shared__ float ss[4], sm[4];
    int wid = threadIdx.x >> 6, lane = threadIdx.x & 63;
    if (lane == 0) { ss[wid] = s; sm[wid] = mx; }
    __syncthreads();
    if (threadIdx.x == 0) {
        float S = ss[0] + ss[1] + ss[2] + ss[3];
        float M = fmaxf(fmaxf(sm[0], sm[1]), fmaxf(sm[2], sm[3]));
        avgv[bc] = S * (1.f / HWSZ);
        maxv[bc] = M;
    }
}

// ---------------------------------------------------------------- CA MLP (tiny)
__global__ __launch_bounds__(256) void ca_mlp_kernel(
    const float* __restrict__ avgv, const float* __restrict__ maxv,
    const float* __restrict__ aw1, const float* __restrict__ ab1,
    const float* __restrict__ aw2, const float* __restrict__ ab2,
    const float* __restrict__ mw1, const float* __restrict__ mb1,
    const float* __restrict__ mw2, const float* __restrict__ mb2,
    float* __restrict__ gate) {
    int b = blockIdx.x;
    __shared__ float av[256], mv[256], ha[16], hm[16];
    int t = threadIdx.x;
    av[t] = avgv[b * 256 + t];
    mv[t] = maxv[b * 256 + t];
    __syncthreads();
    if (t < 16) {
        float s = ab1[t];
        for (int i = 0; i < 256; ++i) s += aw1[t * 256 + i] * av[i];
        ha[t] = fmaxf(s, 0.f);
    } else if (t < 32) {
        int r = t - 16;
        float s = mb1[r];
        for (int i = 0; i < 256; ++i) s += mw1[r * 256 + i] * mv[i];
        hm[r] = fmaxf(s, 0.f);
    }
    __syncthreads();
    float ya = ab2[t], ym = mb2[t];
    for (int r = 0; r < 16; ++r) {
        ya += aw2[t * 16 + r] * ha[r];
        ym += mw2[t * 16 + r] * hm[r];
    }
    float g = ya + ym;
    gate[b * 256 + t] = 1.f / (1.f + __expf(-g));
}

// ---------------------------------------------------------------- attention logits+softmax (MFMA)
// per (b,h): L[i,j] = sum_c Q[c,i]*S[c,j], softmax over j.
// A = Q-tile (rows=i), B = S-tile (rows=j). Wave wr owns rows [wr*32, wr*32+32).
// D: col = j = ni*16 + (lane&15); row = i = wr*32 + mi*16 + 4*(lane>>4) + r.
// Each softmax row lives in one 16-lane group -> shfl_xor(m<16) reduce.
template<bool STORE_M>
__global__ __launch_bounds__(256) void attn_kernel(
    const bf16* __restrict__ Q, const bf16* __restrict__ S,
    bf16* __restrict__ Mout, float* __restrict__ m0out)
{
    int bh = blockIdx.x; int b = bh >> 7, h = bh & 127;
    const bf16* Qb = Q + (size_t)b * CC * HWSZ + h * WW;
    const bf16* Sb = S + (size_t)b * CC * HWSZ + h * WW;
    __shared__ __align__(16) short Qs[128 * LDK];
    __shared__ __align__(16) short Ss[128 * LDK];
    const int tid = threadIdx.x;
    const int lane = tid & 63, wave = tid >> 6;
    const int lrow = lane & 15, lg = lane >> 4;

    f32x4 acc[2][8];
#pragma unroll
    for (int mi = 0; mi < 2; ++mi)
#pragma unroll
        for (int ni = 0; ni < 8; ++ni) acc[mi][ni] = (f32x4)(0.f);

    for (int kt = 0; kt < 4; ++kt) {
        const int k0 = kt * 64;
        // columns of Q/S at fixed h: element (c, x) at src[c*HWSZ + x]
        {   // inline stage (no scale), same pattern as stage_X
            const int xp = tid & 127, xkh = (tid >> 7) * 32;
            const bf16* sq = Qb + (size_t)(k0 + xkh) * HWSZ + xp;
            const bf16* ssrc = Sb + (size_t)(k0 + xkh) * HWSZ + xp;
            short* dq = Qs + xp * LDK + xkh;
            short* ds = Ss + xp * LDK + xkh;
#pragma unroll
            for (int ch = 0; ch < 2; ++ch) {
#pragma unroll
                for (int g = 0; g < 4; ++g) {
                    unsigned short uq[4], us[4];
#pragma unroll
                    for (int r = 0; r < 4; ++r) {
                        int kloc = ch * 16 + g * 4 + r;
                        bfu cq; cq.b = sq[(size_t)kloc * HWSZ]; uq[r] = cq.u;
                        bfu cs2; cs2.b = ssrc[(size_t)kloc * HWSZ]; us[r] = cs2.u;
                    }
                    uint2 wq, ws;
                    wq.x = (unsigned)uq[0] | ((unsigned)uq[1] << 16);
                    wq.y = (unsigned)uq[2] | ((unsigned)uq[3] << 16);
                    ws.x = (unsigned)us[0] | ((unsigned)us[1] << 16);
                    ws.y = (unsigned)us[2] | ((unsigned)us[3] << 16);
                    *(uint2*)(dq + g * 8 + ch * 4) = wq;
                    *(uint2*)(ds + g * 8 + ch * 4) = ws;
                }
            }
        }
        __syncthreads();
#pragma unroll
        for (int kk = 0; kk < 2; ++kk) {
            short8v qa[2], sv[8];
#pragma unroll
            for (int mi = 0; mi < 2; ++mi)
                qa[mi] = *(const short8v*)&Qs[(wave * 32 + mi * 16 + lrow) * LDK + kk * 32 + lg * 8];
#pragma unroll
            for (int ni = 0; ni < 8; ++ni)
                sv[ni] = *(const short8v*)&Ss[(ni * 16 + lrow) * LDK + kk * 32 + lg * 8];
#pragma unroll
            for (int mi = 0; mi < 2; ++mi)
#pragma unroll
                for (int ni = 0; ni < 8; ++ni)
                    acc[mi][ni] = __builtin_amdgcn_mfma_f32_16x16x32_bf16(qa[mi], sv[ni], acc[mi][ni], 0, 0, 0);
        }
        __syncthreads();
    }

    // softmax over j (cols): per (mi, r) row, values = 8 ni per lane x 16 lanes (lrow)
#pragma unroll
    for (int mi = 0; mi < 2; ++mi) {
#pragma unroll
        for (int r = 0; r < 4; ++r) {
            float mx = acc[mi][0][r];
#pragma unroll
            for (int ni = 1; ni < 8; ++ni) mx = fmaxf(mx, acc[mi][ni][r]);
            for (int m = 1; m < 16; m <<= 1) mx = fmaxf(mx, __shfl_xor(mx, m));
            float sm = 0.f;
#pragma unroll
            for (int ni = 0; ni < 8; ++ni) {
                float e = __expf(acc[mi][ni][r] - mx);
                acc[mi][ni][r] = e; sm += e;
            }
            for (int m = 1; m < 16; m <<= 1) sm += __shfl_xor(sm, m);
            float inv = 1.f / sm;
#pragma unroll
            for (int ni = 0; ni < 8; ++ni) acc[mi][ni][r] *= inv;
        }
    }

    if (STORE_M) {
        bf16* Mb = Mout + (size_t)bh * WW * WW;
#pragma unroll
        for (int mi = 0; mi < 2; ++mi)
#pragma unroll
            for (int r = 0; r < 4; ++r) {
                int i = wave * 32 + mi * 16 + lg * 4 + r;
#pragma unroll
                for (int ni = 0; ni < 8; ++ni)
                    stf(&Mb[i * WW + ni * 16 + lrow], acc[mi][ni][r]);
            }
    } else {
        __shared__ float cs[16][128];
#pragma unroll
        for (int ni = 0; ni < 8; ++ni) {
            float s = 0.f;
#pragma unroll
            for (int mi = 0; mi < 2; ++mi)
#pragma unroll
                for (int r = 0; r < 4; ++r) s += acc[mi][ni][r];
            cs[wave * 4 + lg][ni * 16 + lrow] = s;
        }
        __syncthreads();
        if (tid < 128) {
            float s = 0.f;
#pragma unroll
            for (int g = 0; g < 16; ++g) s += cs[g][tid];
            m0out[(size_t)b * HWSZ + h * WW + tid] = (s > 0.1f) ? 0.f : 1.f;
        }
    }
}

// ---------------------------------------------------------------- attention apply (MFMA)
// out[c,i] = sum_j M[i,j] * V[c,j].  A = M-tile (rows=i), B = V-tile (rows=c).
// D: col = c, row = i (4 consecutive i per lane -> 8B packed stores).
__global__ __launch_bounds__(256) void attn_apply_kernel(
    const bf16* __restrict__ Mbuf, const bf16* __restrict__ v3,
    bf16* __restrict__ outb)
{
    int bh = blockIdx.x; int b = bh >> 7, h = bh & 127;
    int ch0 = blockIdx.y * 128;
    const bf16* Mb = Mbuf + (size_t)bh * WW * WW;
    const bf16* Vb = v3 + ((size_t)b * CC + ch0) * HWSZ + h * WW;
    bf16* Ob = outb + ((size_t)b * CC + ch0) * HWSZ + h * WW;
    __shared__ __align__(16) short Ms[128 * LDK];
    __shared__ __align__(16) short Vs[128 * LDK];
    const int tid = threadIdx.x;
    const int lane = tid & 63, wave = tid >> 6;
    const int lrow = lane & 15, lg = lane >> 4;

    f32x4 acc[2][8];
#pragma unroll
    for (int mi = 0; mi < 2; ++mi)
#pragma unroll
        for (int ni = 0; ni < 8; ++ni) acc[mi][ni] = (f32x4)(0.f);

    for (int kt = 0; kt < 2; ++kt) {
        const int k0 = kt * 64;
        stage_rm(Ms, Mb, WW, k0, tid);    // M rows are j-contiguous
        stage_rm(Vs, Vb, HWSZ, k0, tid);  // V rows are j-contiguous
        __syncthreads();
#pragma unroll
        for (int kk = 0; kk < 2; ++kk) {
            short8v ma[2], vv[8];
#pragma unroll
            for (int mi = 0; mi < 2; ++mi)
                ma[mi] = *(const short8v*)&Ms[(wave * 32 + mi * 16 + lrow) * LDK + kk * 32 + lg * 8];
#pragma unroll
            for (int ni = 0; ni < 8; ++ni)
                vv[ni] = *(const short8v*)&Vs[(ni * 16 + lrow) * LDK + kk * 32 + lg * 8];
#pragma unroll
            for (int mi = 0; mi < 2; ++mi)
#pragma unroll
                for (int ni = 0; ni < 8; ++ni)
                    acc[mi][ni] = __builtin_amdgcn_mfma_f32_16x16x32_bf16(ma[mi], vv[ni], acc[mi][ni], 0, 0, 0);
        }
        __syncthreads();
    }

#pragma unroll
    for (int ni = 0; ni < 8; ++ni) {
        const int c = ni * 16 + lrow;
#pragma unroll
        for (int mi = 0; mi < 2; ++mi) {
            const int i0 = wave * 32 + mi * 16 + lg * 4;
            float vals[4] = { acc[mi][ni][0], acc[mi][ni][1], acc[mi][ni][2], acc[mi][ni][3] };
            store4(&Ob[(size_t)c * HWSZ + i0], vals);
        }
    }
}

// ---------------------------------------------------------------- morphology
__global__ void morph_kernel(const float* __restrict__ in, float* __restrict__ out,
                             int Hd, int Wd, int r, float thresh) {
    int idx = blockIdx.x * 256 + threadIdx.x;
    int tot = BB * Hd * Wd;
    if (idx >= tot) return;
    int x = idx % Wd; int y = (idx / Wd) % Hd; int b = idx / (Wd * Hd);
    const float* base = in + (size_t)b * Hd * Wd;
    float s = 0.f;
    for (int dy = -r; dy <= r; ++dy) {
        int yy = y + dy; if (yy < 0 || yy >= Hd) continue;
        for (int dx = -r; dx <= r; ++dx) {
            if (dx * dx + dy * dy > r * r) continue;
            int xx = x + dx; if (xx < 0 || xx >= Wd) continue;
            s += base[yy * Wd + xx];
        }
    }
    out[idx] = (s > thresh) ? 1.f : 0.f;
}

__global__ void pad3_kernel(const float* __restrict__ in, float* __restrict__ out) {
    int idx = blockIdx.x * 256 + threadIdx.x;
    int tot = BB * 134 * 134; if (idx >= tot) return;
    int x = idx % 134; int y = (idx / 134) % 134; int b = idx / (134 * 134);
    float v = 0.f;
    int xs = x - 3, ys = y - 3;
    if (xs >= 0 && xs < 128 && ys >= 0 && ys < 128)
        v = in[((size_t)b * 128 + ys) * 128 + xs];
    out[idx] = v;
}

__global__ void vfinal_kernel(const float* __restrict__ in, float* __restrict__ V) {
    int idx = blockIdx.x * 256 + threadIdx.x; // B*HWSZ
    if (idx >= BB * HWSZ) return;
    int x = idx & 127; int y = (idx >> 7) & 127; int b = idx >> 14;
    V[idx] = 1.f - in[((size_t)b * 134 + y + 3) * 134 + (x + 3)];
}

// ---------------------------------------------------------------- launch
extern "C" void kernel_launch(void* const* d_in, const int* in_sizes, int n_in,
                              void* d_out, int out_size, void* d_ws, size_t ws_size,
                              hipStream_t stream) {
    const float* x_p   = (const float*)d_in[0];
    const float* x_c   = (const float*)d_in[1];
    const float* pa_w1 = (const float*)d_in[2];
    const float* pa_b1 = (const float*)d_in[3];
    const float* pa_w2 = (const float*)d_in[4];
    const float* pa_b2 = (const float*)d_in[5];
    const float* pa_wc = (const float*)d_in[6];
    const float* pa_bc = (const float*)d_in[7];
    const float* ca_aw1 = (const float*)d_in[8];
    const float* ca_ab1 = (const float*)d_in[9];
    const float* ca_aw2 = (const float*)d_in[10];
    const float* ca_ab2 = (const float*)d_in[11];
    const float* ca_mw1 = (const float*)d_in[12];
    const float* ca_mb1 = (const float*)d_in[13];
    const float* ca_mw2 = (const float*)d_in[14];
    const float* ca_mb2 = (const float*)d_in[15];
    const float* b1_w  = (const float*)d_in[16];
    const float* b1_b  = (const float*)d_in[17];
    const float* b2_w  = (const float*)d_in[18];
    const float* b2_b  = (const float*)d_in[19];
    const float* b3_w  = (const float*)d_in[20];
    const float* b3_b  = (const float*)d_in[21];
    const float* fus_w = (const float*)d_in[22];
    const float* fus_b = (const float*)d_in[23];
    float* out = (float*)d_out;

    char* wsb = (char*)d_ws;
    bf16* A  = (bf16*)wsb;                    // NTOT bf16 (64 MiB)
    bf16* Bb = (bf16*)(wsb + NTOT * 2);       // NTOT bf16 (64 MiB)
    float* smalls = (float*)(wsb + NTOT * 4);
    float* avgv = smalls;                     // 2048
    float* maxv = smalls + 2048;              // 2048
    float* gate = smalls + 4096;              // 2048
    float* mph0 = smalls + 6144;              // 143648
    float* mph1 = mph0 + 143648;              // 143648
    float* Vfin = mph1 + 143648;              // 131072
    bf16* D1 = (bf16*)d_out;                  // NTOT bf16
    bf16* D2 = D1 + NTOT;                     // NTOT bf16
    bf16* Mbuf = D1;                          // 16.7M bf16 (32 MiB)

    dim3 cgrid(HWSZ / BMP, CC / BNO, BB);     // (128, 2, 8)
    const int TPB = 256;

    // --- PALayer ---
    pool3_kernel<<<NTOT / 8 / 256, TPB, 0, stream>>>(x_p, A, Bb); // y1->A, y2->Bb
    conv1x1_kernel<EPI_RELU, false, false, false, bf16, bf16, bf16, bf16>
        <<<cgrid, TPB, 0, stream>>>(D1, A, nullptr, pa_w1, 256, pa_b1,
                                    nullptr, nullptr, nullptr, nullptr);          // z1->D1
    conv1x1_kernel<EPI_ADDAUX, false, false, false, bf16, bf16, bf16, bf16>
        <<<cgrid, TPB, 0, stream>>>(D2, D1, nullptr, pa_w2, 256, pa_b2,
                                    A, nullptr, nullptr, nullptr);                // u=conv(z1)+y1 ->D2
    conv1x1_kernel<EPI_RELU, false, false, false, bf16, bf16, bf16, bf16>
        <<<cgrid, TPB, 0, stream>>>(A, Bb, nullptr, pa_w1, 256, pa_b1,
                                    nullptr, nullptr, nullptr, nullptr);          // z2->A
    conv1x1_kernel<EPI_ADDAUX, false, false, false, bf16, bf16, bf16, bf16>
        <<<cgrid, TPB, 0, stream>>>(D1, A, nullptr, pa_w2, 256, pa_b2,
                                    Bb, nullptr, nullptr, nullptr);               // v=conv(z2)+y2 ->D1
    conv1x1_kernel<EPI_SIGMUL, true, false, false, bf16, bf16, float, bf16>
        <<<cgrid, TPB, 0, stream>>>(A, D2, D1, pa_wc, 512, pa_bc,
                                    x_p, nullptr, nullptr, nullptr);              // buffer_p->A

    // --- CALayer gate ---
    ca_reduce_kernel<<<BB * CC, TPB, 0, stream>>>(x_c, avgv, maxv);
    ca_mlp_kernel<<<BB, TPB, 0, stream>>>(avgv, maxv, ca_aw1, ca_ab1, ca_aw2, ca_ab2,
                                          ca_mw1, ca_mb1, ca_mw2, ca_mb2, gate);

    // --- Q/S projections ---
    conv1x1_kernel<EPI_NONE, false, false, false, bf16, bf16, bf16, bf16>
        <<<cgrid, TPB, 0, stream>>>(Bb, A, nullptr, b1_w, 256, b1_b,
                                    nullptr, nullptr, nullptr, nullptr);          // Q1->Bb
    conv1x1_kernel<EPI_NONE, false, false, false, bf16, bf16, bf16, bf16>
        <<<cgrid, TPB, 0, stream>>>(D1, A, nullptr, b2_w, 256, b2_b,
                                    nullptr, nullptr, nullptr, nullptr);          // S2->D1
    conv1x1_kernel<EPI_NONE, false, true, false, float, float, float, bf16>
        <<<cgrid, TPB, 0, stream>>>(A, x_c, nullptr, b1_w, 256, b1_b,
                                    nullptr, gate, nullptr, nullptr);             // Q2->A
    conv1x1_kernel<EPI_NONE, false, true, false, float, float, float, bf16>
        <<<cgrid, TPB, 0, stream>>>(D2, x_c, nullptr, b2_w, 256, b2_b,
                                    nullptr, gate, nullptr, nullptr);             // S1->D2

    // --- attention softmaxes ---
    attn_kernel<false><<<BB * HH, TPB, 0, stream>>>(A, D1, nullptr, mph0);  // M_p_to_c colsum -> m0
    attn_kernel<true><<<BB * HH, TPB, 0, stream>>>(Bb, D2, Mbuf, nullptr);  // M_c_to_p -> Mbuf (D1)

    // --- v3 ---
    conv1x1_kernel<EPI_NONE, false, false, false, float, float, float, bf16>
        <<<cgrid, TPB, 0, stream>>>(A, x_c, nullptr, b3_w, 256, b3_b,
                                    nullptr, nullptr, nullptr, nullptr);          // v3->A

    // --- morphology (tiny) ---
    morph_kernel<<<512, TPB, 0, stream>>>(mph0, mph1, 128, 128, 2, 12.5f);
    morph_kernel<<<512, TPB, 0, stream>>>(mph1, mph0, 128, 128, 2, 0.5f);
    morph_kernel<<<512, TPB, 0, stream>>>(mph0, mph1, 128, 128, 1, 0.5f);
    morph_kernel<<<512, TPB, 0, stream>>>(mph1, mph0, 128, 128, 1, 4.5f);
    pad3_kernel<<<562, TPB, 0, stream>>>(mph0, mph1);
    morph_kernel<<<562, TPB, 0, stream>>>(mph1, mph0, 134, 134, 3, 0.5f);
    morph_kernel<<<562, TPB, 0, stream>>>(mph0, mph1, 134, 134, 3, 28.5f);
    vfinal_kernel<<<512, TPB, 0, stream>>>(mph1, Vfin);

    // --- attend + fusion ---
    attn_apply_kernel<<<dim3(BB * HH, 2), TPB, 0, stream>>>(Mbuf, A, Bb);
    conv1x1_kernel<EPI_NONE, true, false, true, bf16, float, float, float>
        <<<cgrid, TPB, 0, stream>>>(out, Bb, x_p, fus_w, 513, fus_b,
                                    nullptr, nullptr, Vfin, fus_w + 512);         // final -> d_out fp32
}

// Round 3
// 1413.642 us; speedup vs baseline: 2.8911x; 1.1056x over previous
//
#include <hip/hip_runtime.h>
#include <hip/hip_bf16.h>
#include <math.h>

#define BB 8
#define CC 256
#define HH 128
#define WW 128
#define HWSZ (HH*WW)              // 16384
#define NTOT ((size_t)BB*CC*HWSZ) // 33554432 elements

typedef __hip_bfloat16 bf16;
typedef __attribute__((ext_vector_type(8))) short short8v; // 8 bf16 = 4 VGPR (MFMA A/B frag)
typedef __attribute__((ext_vector_type(4))) float f32x4;   // MFMA C/D frag

__device__ __forceinline__ float ldf(const float* p) { return *p; }
__device__ __forceinline__ float ldf(const bf16* p) { return __bfloat162float(*p); }
__device__ __forceinline__ void stf(float* p, float v) { *p = v; }
__device__ __forceinline__ void stf(bf16* p, float v) { *p = __float2bfloat16(v); }

union bfu { bf16 b; unsigned short u; };
__device__ __forceinline__ unsigned short f2bf_bits(float v) { bfu c; c.b = __float2bfloat16(v); return c.u; }
__device__ __forceinline__ float bfbits2f(unsigned short u) { bfu c; c.u = u; return __bfloat162float(c.b); }
__device__ __forceinline__ unsigned pk2(float a, float b) {
    return (unsigned)f2bf_bits(a) | ((unsigned)f2bf_bits(b) << 16);
}

// global->LDS direct DMA, 16B per lane. LDS dest = wave-uniform base + lane*16.
__device__ __forceinline__ void gld16(const void* g, void* l) {
    __builtin_amdgcn_global_load_lds(
        (const __attribute__((address_space(1))) unsigned int*)(uintptr_t)g,
        (__attribute__((address_space(3))) unsigned int*)(uintptr_t)l, 16, 0, 0);
}

// ---------------------------------------------------------------- pool 3x3
__global__ __launch_bounds__(256) void pool3_kernel(const float* __restrict__ x,
                                                    bf16* __restrict__ yavg,
                                                    bf16* __restrict__ ymax) {
    size_t idx = (size_t)blockIdx.x * 256 + threadIdx.x; // over NTOT/8
    int w0 = (int)(idx & 15) * 8;
    int h = (int)(idx >> 4) & 127;
    size_t bc = idx >> 11;
    const float* base = x + bc * HWSZ;
    float ts[8], tm[8];
#pragma unroll
    for (int i = 0; i < 8; ++i) { ts[i] = 0.f; tm[i] = -INFINITY; }
#pragma unroll
    for (int dy = -1; dy <= 1; ++dy) {
        int hh = h + dy;
        if (hh < 0 || hh >= HH) continue;
        const float* rp = base + hh * WW + w0;
        float4 v0 = *(const float4*)rp;
        float4 v1 = *(const float4*)(rp + 4);
        float s9[10], m9[10];
        s9[1] = v0.x; s9[2] = v0.y; s9[3] = v0.z; s9[4] = v0.w;
        s9[5] = v1.x; s9[6] = v1.y; s9[7] = v1.z; s9[8] = v1.w;
#pragma unroll
        for (int i = 1; i < 9; ++i) m9[i] = s9[i];
        if (w0 > 0)      { float L = rp[-1]; s9[0] = L; m9[0] = L; }
        else             { s9[0] = 0.f; m9[0] = -INFINITY; }
        if (w0 < WW - 8) { float R = rp[8]; s9[9] = R; m9[9] = R; }
        else             { s9[9] = 0.f; m9[9] = -INFINITY; }
#pragma unroll
        for (int i = 0; i < 8; ++i) {
            ts[i] += s9[i] + s9[i + 1] + s9[i + 2];
            tm[i] = fmaxf(tm[i], fmaxf(m9[i], fmaxf(m9[i + 1], m9[i + 2])));
        }
    }
    uint4 ua, um;
    ua.x = pk2(ts[0] * (1.f/9.f), ts[1] * (1.f/9.f));
    ua.y = pk2(ts[2] * (1.f/9.f), ts[3] * (1.f/9.f));
    ua.z = pk2(ts[4] * (1.f/9.f), ts[5] * (1.f/9.f));
    ua.w = pk2(ts[6] * (1.f/9.f), ts[7] * (1.f/9.f));
    um.x = pk2(tm[0], tm[1]); um.y = pk2(tm[2], tm[3]);
    um.z = pk2(tm[4], tm[5]); um.w = pk2(tm[6], tm[7]);
    *(uint4*)(yavg + idx * 8) = ua;
    *(uint4*)(ymax + idx * 8) = um;
}

// ---------------------------------------------------------------- weight prep
// Convert all 7 fp32 weight matrices -> bf16 hi|lo planes, pre-permuted for the
// MFMA fragment layout and pre-XOR-swizzled for bank-conflict-free LDS, stored
// as the exact LDS tile image so conv stages W via global_load_lds (pure DMA).
// Layout per matrix (shorts): hi plane [o>>7][kt][o&127][64], lo plane at +256*K.
// Within a 64-k tile: pos = (k6>>5)*32 + ((k5>>2)&3)*8 + (k5>>4)*4 + (k5&3),
// then pos ^= (o&7)<<3   (k5 = k6&31).
__global__ __launch_bounds__(256) void prep_w_kernel(
    const float* __restrict__ w0, const float* __restrict__ w1,
    const float* __restrict__ w2, const float* __restrict__ w3,
    const float* __restrict__ w4, const float* __restrict__ w5,
    const float* __restrict__ w6, short* __restrict__ dst)
{
    int gid = blockIdx.x * 256 + threadIdx.x;  // 0..589823
    const float* src; int K, WS, local; size_t dofs;
    if (gid < 65536)       { src = w0; K = 256; WS = 256; dofs = 0;      local = gid; }
    else if (gid < 131072) { src = w1; K = 256; WS = 256; dofs = 131072; local = gid - 65536; }
    else if (gid < 262144) { src = w2; K = 512; WS = 512; dofs = 262144; local = gid - 131072; }
    else if (gid < 327680) { src = w3; K = 256; WS = 256; dofs = 524288; local = gid - 262144; }
    else if (gid < 393216) { src = w4; K = 256; WS = 256; dofs = 655360; local = gid - 327680; }
    else if (gid < 458752) { src = w5; K = 256; WS = 256; dofs = 786432; local = gid - 393216; }
    else                   { src = w6; K = 512; WS = 513; dofs = 917504; local = gid - 458752; }
    int o = (K == 256) ? (local >> 8) : (local >> 9);
    int k = local & (K - 1);
    int kt = k >> 6, k6 = k & 63, k5 = k6 & 31;
    int pos = (k6 >> 5) * 32 + ((k5 >> 2) & 3) * 8 + (k5 >> 4) * 4 + (k5 & 3);
    pos ^= (o & 7) << 3;
    size_t off = dofs + (size_t)(o >> 7) * K * 128 + (size_t)kt * 8192 + (size_t)(o & 127) * 64 + pos;
    float v = src[(size_t)o * WS + k];
    unsigned short hb = f2bf_bits(v);
    dst[off] = (short)hb;
    dst[off + (size_t)256 * K] = (short)f2bf_bits(v - bfbits2f(hb));
}

// ---------------------------------------------------------------- conv1x1 MFMA GEMM
// D[pixel][o] = X^T[pixel][k] * W^T[k][o].  v_mfma_f32_16x16x32_bf16.
// LDS: LDK=64 + XOR swizzle (chunk ^= (row&7)<<3) on both store and frag read.
#define EPI_NONE   0
#define EPI_RELU   1
#define EPI_ADDAUX 2
#define EPI_SIGMUL 3

#define BMP 128   // pixels per block tile (M)
#define BNO 128   // out-chans per block tile (N)

template<bool SC, class T>
__device__ __forceinline__ unsigned short ld_bits(const T* p, float s);
template<> __device__ __forceinline__ unsigned short ld_bits<false, bf16>(const bf16* p, float) {
    bfu c; c.b = *p; return c.u;
}
template<> __device__ __forceinline__ unsigned short ld_bits<true, bf16>(const bf16* p, float s) {
    return f2bf_bits(__bfloat162float(*p) * s);
}
template<> __device__ __forceinline__ unsigned short ld_bits<false, float>(const float* p, float) {
    return f2bf_bits(*p);
}
template<> __device__ __forceinline__ unsigned short ld_bits<true, float>(const float* p, float s) {
    return f2bf_bits(*p * s);
}

// stage X tile: 128 pixels x 64 k from channel-major [k][pixel] source,
// k-permuted + swizzled, one ds_write_b128 per 8-short chunk.
template<bool SC, class T>
__device__ __forceinline__ void stage_X(short* __restrict__ Xs,
                                        const T* __restrict__ in,
                                        const float* __restrict__ scale,
                                        int b, int cbase, size_t pbase, int tid)
{
    const int xp  = tid & 127;
    const int xkh = (tid >> 7) * 32;
    const T* src = in + ((size_t)b * 256 + cbase + xkh) * HWSZ + pbase + xp;
    const float* scp = SC ? (scale + b * 256 + cbase + xkh) : nullptr;
    const int swz = (xp & 7) << 3;
    short* dst = Xs + xp * 64;
#pragma unroll
    for (int g = 0; g < 4; ++g) {
        unsigned short u[8];
#pragma unroll
        for (int j = 0; j < 8; ++j) {
            int k5 = (j >> 2) * 16 + g * 4 + (j & 3);
            u[j] = ld_bits<SC, T>(src + (size_t)k5 * HWSZ, SC ? scp[k5] : 1.f);
        }
        uint4 wv;
        wv.x = (unsigned)u[0] | ((unsigned)u[1] << 16);
        wv.y = (unsigned)u[2] | ((unsigned)u[3] << 16);
        wv.z = (unsigned)u[4] | ((unsigned)u[5] << 16);
        wv.w = (unsigned)u[6] | ((unsigned)u[7] << 16);
        *(uint4*)(dst + ((xkh + g * 8) ^ swz)) = wv;
    }
}

// stage from row-major (k-contiguous) bf16 source into permuted+swizzled LDS
__device__ __forceinline__ void stage_rm(short* __restrict__ Xs, const bf16* __restrict__ src,
                                         size_t rstride, int k0, int tid)
{
    const int row = tid & 127;
    const int kh = (tid >> 7) * 32;
    const short* sp = (const short*)src + (size_t)row * rstride + k0 + kh;
    const int swz = (row & 7) << 3;
    short* dst = Xs + row * 64;
    short8v lv[4];
#pragma unroll
    for (int q = 0; q < 4; ++q) lv[q] = *(const short8v*)(sp + q * 8);
#pragma unroll
    for (int g = 0; g < 4; ++g) {
        unsigned short u[8];
#pragma unroll
        for (int r = 0; r < 4; ++r) {
            u[r]     = (unsigned short)lv[g >> 1][(g & 1) * 4 + r];
            u[4 + r] = (unsigned short)lv[2 + (g >> 1)][(g & 1) * 4 + r];
        }
        uint4 wv;
        wv.x = (unsigned)u[0] | ((unsigned)u[1] << 16);
        wv.y = (unsigned)u[2] | ((unsigned)u[3] << 16);
        wv.z = (unsigned)u[4] | ((unsigned)u[5] << 16);
        wv.w = (unsigned)u[6] | ((unsigned)u[7] << 16);
        *(uint4*)(dst + ((kh + g * 8) ^ swz)) = wv;
    }
}

__device__ __forceinline__ void load4f(const bf16* p, float* v) {
    ushort4 u = *(const ushort4*)p;
    v[0] = bfbits2f(u.x); v[1] = bfbits2f(u.y); v[2] = bfbits2f(u.z); v[3] = bfbits2f(u.w);
}
__device__ __forceinline__ void load4f(const float* p, float* v) {
    float4 u = *(const float4*)p;
    v[0] = u.x; v[1] = u.y; v[2] = u.z; v[3] = u.w;
}
__device__ __forceinline__ void store4(bf16* p, const float* v) {
    uint2 u;
    u.x = pk2(v[0], v[1]);
    u.y = pk2(v[2], v[3]);
    *(uint2*)p = u;
}
__device__ __forceinline__ void store4(float* p, const float* v) {
    *(float4*)p = make_float4(v[0], v[1], v[2], v[3]);
}

template<int MODE, bool TWO_IN, bool HAS_SCALE, bool HAS_V,
         class TIN1, class TIN2, class TAUX, class TOUT>
__global__ __launch_bounds__(256) void conv1x1_kernel(
    TOUT* __restrict__ out,
    const TIN1* __restrict__ in1,
    const TIN2* __restrict__ in2,
    const short* __restrict__ Wp,      // prepped bf16 hi|lo tile image
    const float* __restrict__ bias,
    const TAUX* __restrict__ aux,
    const float* __restrict__ scale,   // per (b, in-chan) gate
    const float* __restrict__ vvec,    // per (b, pixel) scalar (V column)
    const float* __restrict__ vw, int vws)  // fp32 V-weight column, stride vws
{
    const int K = TWO_IN ? 512 : 256;
    __shared__ __align__(16) short Xs[BMP * 64];
    __shared__ __align__(16) short Wh[BNO * 64];
    __shared__ __align__(16) short Wl[BNO * 64];
    const int tid = threadIdx.x;
    const int b = blockIdx.z;
    const size_t p0 = (size_t)blockIdx.x * BMP;
    const int o0 = blockIdx.y * BNO;
    const int lane = tid & 63;
    const int wave = tid >> 6;
    const int wr = wave >> 1, wc = wave & 1;   // wave sub-tile: 64 px x 64 o
    const int lrow = lane & 15, lg = lane >> 4;
    const int sA = (lrow & 7) << 3;

    f32x4 acc[4][4];
#pragma unroll
    for (int mi = 0; mi < 4; ++mi)
#pragma unroll
        for (int ni = 0; ni < 4; ++ni) acc[mi][ni] = (f32x4)(0.f);

    for (int kt = 0; kt < K / 64; ++kt) {
        const int k0 = kt * 64;
        // ---- W tiles via global_load_lds DMA (16KB hi + 16KB lo) ----
        {
            const short* gWh = Wp + (size_t)(o0 >> 7) * K * 128 + (size_t)kt * 8192;
            const short* gWl = gWh + (size_t)256 * K;
            const int wofs = wave * 4096;
            const int lb = lane * 16;
#pragma unroll
            for (int q = 0; q < 4; ++q) {
                gld16((const char*)gWh + wofs + q * 1024 + lb, (char*)Wh + wofs + q * 1024);
                gld16((const char*)gWl + wofs + q * 1024 + lb, (char*)Wl + wofs + q * 1024);
            }
        }
        if (TWO_IN && k0 >= 256)
            stage_X<false, TIN2>(Xs, in2, nullptr, b, k0 - 256, p0, tid);
        else
            stage_X<HAS_SCALE, TIN1>(Xs, in1, scale, b, k0, p0, tid);
        __syncthreads();
#pragma unroll
        for (int kk = 0; kk < 2; ++kk) {
            const int kofs = kk * 32 + lg * 8;
            short8v af[4], bh[4], bl[4];
#pragma unroll
            for (int mi = 0; mi < 4; ++mi)
                af[mi] = *(const short8v*)&Xs[(wr * 64 + mi * 16 + lrow) * 64 + (kofs ^ sA)];
#pragma unroll
            for (int ni = 0; ni < 4; ++ni) {
                bh[ni] = *(const short8v*)&Wh[(wc * 64 + ni * 16 + lrow) * 64 + (kofs ^ sA)];
                bl[ni] = *(const short8v*)&Wl[(wc * 64 + ni * 16 + lrow) * 64 + (kofs ^ sA)];
            }
#pragma unroll
            for (int mi = 0; mi < 4; ++mi)
#pragma unroll
                for (int ni = 0; ni < 4; ++ni)
                    acc[mi][ni] = __builtin_amdgcn_mfma_f32_16x16x32_bf16(af[mi], bh[ni], acc[mi][ni], 0, 0, 0);
#pragma unroll
            for (int mi = 0; mi < 4; ++mi)
#pragma unroll
                for (int ni = 0; ni < 4; ++ni)
                    acc[mi][ni] = __builtin_amdgcn_mfma_f32_16x16x32_bf16(af[mi], bl[ni], acc[mi][ni], 0, 0, 0);
        }
        __syncthreads();
    }

    // epilogue: lane holds, per (mi,ni) frag, 4 CONSECUTIVE pixels at fixed o
#pragma unroll
    for (int ni = 0; ni < 4; ++ni) {
        const int o = o0 + wc * 64 + ni * 16 + lrow;
        const float bs = bias[o];
        const float vwo = HAS_V ? vw[(size_t)o * vws] : 0.f;
#pragma unroll
        for (int mi = 0; mi < 4; ++mi) {
            const size_t p = p0 + wr * 64 + mi * 16 + lg * 4;
            const size_t oidx = ((size_t)b * CC + o) * HWSZ + p;
            float auxv[4];
            if (MODE == EPI_ADDAUX || MODE == EPI_SIGMUL) load4f(&aux[oidx], auxv);
            float vv[4];
            if (HAS_V) load4f(&vvec[(size_t)b * HWSZ + p], vv);
            float vals[4];
#pragma unroll
            for (int r = 0; r < 4; ++r) {
                float val = acc[mi][ni][r] + bs;
                if (HAS_V) val += vwo * vv[r];
                if (MODE == EPI_RELU)        val = fmaxf(val, 0.f);
                else if (MODE == EPI_ADDAUX) val += auxv[r];
                else if (MODE == EPI_SIGMUL) val = (1.f / (1.f + __expf(-val))) * auxv[r];
                vals[r] = val;
            }
            store4(&out[oidx], vals);
        }
    }
}

// ---------------------------------------------------------------- CA reduce
__global__ __launch_bounds__(256) void ca_reduce_kernel(const float* __restrict__ xc,
                                                        float* __restrict__ avgv,
                                                        float* __restrict__ maxv) {
    int bc = blockIdx.x; // 0..2047
    const float4* base = (const float4*)(xc + (size_t)bc * HWSZ);
    float s = 0.f, mx = -INFINITY;
    for (int i = threadIdx.x; i < HWSZ / 4; i += 256) {
        float4 v = base[i];
        s += v.x + v.y + v.z + v.w;
        mx = fmaxf(mx, fmaxf(fmaxf(v.x, v.y), fmaxf(v.z, v.w)));
    }
    for (int off = 32; off; off >>= 1) {
        s += __shfl_down(s, off);
        mx = fmaxf(mx, __shfl_down(mx, off));
    }
    __shared__ float ss[4], sm[4];
    int wid = threadIdx.x >> 6, lane = threadIdx.x & 63;
    if (lane == 0) { ss[wid] = s; sm[wid] = mx; }
    __syncthreads();
    if (threadIdx.x == 0) {
        float S = ss[0] + ss[1] + ss[2] + ss[3];
        float M = fmaxf(fmaxf(sm[0], sm[1]), fmaxf(sm[2], sm[3]));
        avgv[bc] = S * (1.f / HWSZ);
        maxv[bc] = M;
    }
}

// ---------------------------------------------------------------- CA MLP (tiny)
__global__ __launch_bounds__(256) void ca_mlp_kernel(
    const float* __restrict__ avgv, const float* __restrict__ maxv,
    const float* __restrict__ aw1, const float* __restrict__ ab1,
    const float* __restrict__ aw2, const float* __restrict__ ab2,
    const float* __restrict__ mw1, const float* __restrict__ mb1,
    const float* __restrict__ mw2, const float* __restrict__ mb2,
    float* __restrict__ gate) {
    int b = blockIdx.x;
    __shared__ float av[256], mv[256], ha[16], hm[16];
    int t = threadIdx.x;
    av[t] = avgv[b * 256 + t];
    mv[t] = maxv[b * 256 + t];
    __syncthreads();
    if (t < 16) {
        float s = ab1[t];
        for (int i = 0; i < 256; ++i) s += aw1[t * 256 + i] * av[i];
        ha[t] = fmaxf(s, 0.f);
    } else if (t < 32) {
        int r = t - 16;
        float s = mb1[r];
        for (int i = 0; i < 256; ++i) s += mw1[r * 256 + i] * mv[i];
        hm[r] = fmaxf(s, 0.f);
    }
    __syncthreads();
    float ya = ab2[t], ym = mb2[t];
    for (int r = 0; r < 16; ++r) {
        ya += aw2[t * 16 + r] * ha[r];
        ym += mw2[t * 16 + r] * hm[r];
    }
    float g = ya + ym;
    gate[b * 256 + t] = 1.f / (1.f + __expf(-g));
}

// ---------------------------------------------------------------- attention logits+softmax (MFMA)
template<bool STORE_M>
__global__ __launch_bounds__(256) void attn_kernel(
    const bf16* __restrict__ Q, const bf16* __restrict__ S,
    bf16* __restrict__ Mout, float* __restrict__ m0out)
{
    int bh = blockIdx.x; int b = bh >> 7, h = bh & 127;
    const bf16* Qb = Q + (size_t)b * CC * HWSZ + h * WW;
    const bf16* Sb = S + (size_t)b * CC * HWSZ + h * WW;
    __shared__ __align__(16) short Qs[128 * 64];
    __shared__ __align__(16) short Ss[128 * 64];
    const int tid = threadIdx.x;
    const int lane = tid & 63, wave = tid >> 6;
    const int lrow = lane & 15, lg = lane >> 4;
    const int sA = (lrow & 7) << 3;

    f32x4 acc[2][8];
#pragma unroll
    for (int mi = 0; mi < 2; ++mi)
#pragma unroll
        for (int ni = 0; ni < 8; ++ni) acc[mi][ni] = (f32x4)(0.f);

    for (int kt = 0; kt < 4; ++kt) {
        const int k0 = kt * 64;
        {
            const int xp = tid & 127, xkh = (tid >> 7) * 32;
            const bf16* sq = Qb + (size_t)(k0 + xkh) * HWSZ + xp;
            const bf16* ssrc = Sb + (size_t)(k0 + xkh) * HWSZ + xp;
            const int swz = (xp & 7) << 3;
            short* dq = Qs + xp * 64;
            short* dsx = Ss + xp * 64;
#pragma unroll
            for (int g = 0; g < 4; ++g) {
                unsigned short uq[8], us[8];
#pragma unroll
                for (int j = 0; j < 8; ++j) {
                    int k5 = (j >> 2) * 16 + g * 4 + (j & 3);
                    bfu cq; cq.b = sq[(size_t)k5 * HWSZ]; uq[j] = cq.u;
                    bfu cs2; cs2.b = ssrc[(size_t)k5 * HWSZ]; us[j] = cs2.u;
                }
                uint4 a, s2;
                a.x = (unsigned)uq[0] | ((unsigned)uq[1] << 16);
                a.y = (unsigned)uq[2] | ((unsigned)uq[3] << 16);
                a.z = (unsigned)uq[4] | ((unsigned)uq[5] << 16);
                a.w = (unsigned)uq[6] | ((unsigned)uq[7] << 16);
                s2.x = (unsigned)us[0] | ((unsigned)us[1] << 16);
                s2.y = (unsigned)us[2] | ((unsigned)us[3] << 16);
                s2.z = (unsigned)us[4] | ((unsigned)us[5] << 16);
                s2.w = (unsigned)us[6] | ((unsigned)us[7] << 16);
                *(uint4*)(dq + ((xkh + g * 8) ^ swz)) = a;
                *(uint4*)(dsx + ((xkh + g * 8) ^ swz)) = s2;
            }
        }
        __syncthreads();
#pragma unroll
        for (int kk = 0; kk < 2; ++kk) {
            const int kofs = (kk * 32 + lg * 8) ^ sA;
            short8v qa[2], sv[8];
#pragma unroll
            for (int mi = 0; mi < 2; ++mi)
                qa[mi] = *(const short8v*)&Qs[(wave * 32 + mi * 16 + lrow) * 64 + kofs];
#pragma unroll
            for (int ni = 0; ni < 8; ++ni)
                sv[ni] = *(const short8v*)&Ss[(ni * 16 + lrow) * 64 + kofs];
#pragma unroll
            for (int mi = 0; mi < 2; ++mi)
#pragma unroll
                for (int ni = 0; ni < 8; ++ni)
                    acc[mi][ni] = __builtin_amdgcn_mfma_f32_16x16x32_bf16(qa[mi], sv[ni], acc[mi][ni], 0, 0, 0);
        }
        __syncthreads();
    }

    // softmax over j (cols): per (mi, r) row, values = 8 ni per lane x 16 lanes
#pragma unroll
    for (int mi = 0; mi < 2; ++mi) {
#pragma unroll
        for (int r = 0; r < 4; ++r) {
            float mx = acc[mi][0][r];
#pragma unroll
            for (int ni = 1; ni < 8; ++ni) mx = fmaxf(mx, acc[mi][ni][r]);
            for (int m = 1; m < 16; m <<= 1) mx = fmaxf(mx, __shfl_xor(mx, m));
            float sm = 0.f;
#pragma unroll
            for (int ni = 0; ni < 8; ++ni) {
                float e = __expf(acc[mi][ni][r] - mx);
                acc[mi][ni][r] = e; sm += e;
            }
            for (int m = 1; m < 16; m <<= 1) sm += __shfl_xor(sm, m);
            float inv = 1.f / sm;
#pragma unroll
            for (int ni = 0; ni < 8; ++ni) acc[mi][ni][r] *= inv;
        }
    }

    if (STORE_M) {
        bf16* Mb = Mout + (size_t)bh * WW * WW;
#pragma unroll
        for (int mi = 0; mi < 2; ++mi)
#pragma unroll
            for (int r = 0; r < 4; ++r) {
                int i = wave * 32 + mi * 16 + lg * 4 + r;
#pragma unroll
                for (int ni = 0; ni < 8; ++ni)
                    stf(&Mb[i * WW + ni * 16 + lrow], acc[mi][ni][r]);
            }
    } else {
        __shared__ float cs[16][128];
#pragma unroll
        for (int ni = 0; ni < 8; ++ni) {
            float s = 0.f;
#pragma unroll
            for (int mi = 0; mi < 2; ++mi)
#pragma unroll
                for (int r = 0; r < 4; ++r) s += acc[mi][ni][r];
            cs[wave * 4 + lg][ni * 16 + lrow] = s;
        }
        __syncthreads();
        if (tid < 128) {
            float s = 0.f;
#pragma unroll
            for (int g = 0; g < 16; ++g) s += cs[g][tid];
            m0out[(size_t)b * HWSZ + h * WW + tid] = (s > 0.1f) ? 0.f : 1.f;
        }
    }
}

// ---------------------------------------------------------------- attention apply (MFMA)
__global__ __launch_bounds__(256) void attn_apply_kernel(
    const bf16* __restrict__ Mbuf, const bf16* __restrict__ v3,
    bf16* __restrict__ outb)
{
    int bh = blockIdx.x; int b = bh >> 7, h = bh & 127;
    int ch0 = blockIdx.y * 128;
    const bf16* Mb = Mbuf + (size_t)bh * WW * WW;
    const bf16* Vb = v3 + ((size_t)b * CC + ch0) * HWSZ + h * WW;
    bf16* Ob = outb + ((size_t)b * CC + ch0) * HWSZ + h * WW;
    __shared__ __align__(16) short Ms[128 * 64];
    __shared__ __align__(16) short Vs[128 * 64];
    const int tid = threadIdx.x;
    const int lane = tid & 63, wave = tid >> 6;
    const int lrow = lane & 15, lg = lane >> 4;
    const int sA = (lrow & 7) << 3;

    f32x4 acc[2][8];
#pragma unroll
    for (int mi = 0; mi < 2; ++mi)
#pragma unroll
        for (int ni = 0; ni < 8; ++ni) acc[mi][ni] = (f32x4)(0.f);

    for (int kt = 0; kt < 2; ++kt) {
        const int k0 = kt * 64;
        stage_rm(Ms, Mb, WW, k0, tid);    // M rows are j-contiguous
        stage_rm(Vs, Vb, HWSZ, k0, tid);  // V rows are j-contiguous
        __syncthreads();
#pragma unroll
        for (int kk = 0; kk < 2; ++kk) {
            const int kofs = (kk * 32 + lg * 8) ^ sA;
            short8v ma[2], vv[8];
#pragma unroll
            for (int mi = 0; mi < 2; ++mi)
                ma[mi] = *(const short8v*)&Ms[(wave * 32 + mi * 16 + lrow) * 64 + kofs];
#pragma unroll
            for (int ni = 0; ni < 8; ++ni)
                vv[ni] = *(const short8v*)&Vs[(ni * 16 + lrow) * 64 + kofs];
#pragma unroll
            for (int mi = 0; mi < 2; ++mi)
#pragma unroll
                for (int ni = 0; ni < 8; ++ni)
                    acc[mi][ni] = __builtin_amdgcn_mfma_f32_16x16x32_bf16(ma[mi], vv[ni], acc[mi][ni], 0, 0, 0);
        }
        __syncthreads();
    }

#pragma unroll
    for (int ni = 0; ni < 8; ++ni) {
        const int c = ni * 16 + lrow;
#pragma unroll
        for (int mi = 0; mi < 2; ++mi) {
            const int i0 = wave * 32 + mi * 16 + lg * 4;
            float vals[4] = { acc[mi][ni][0], acc[mi][ni][1], acc[mi][ni][2], acc[mi][ni][3] };
            store4(&Ob[(size_t)c * HWSZ + i0], vals);
        }
    }
}

// ---------------------------------------------------------------- morphology
__global__ void morph_kernel(const float* __restrict__ in, float* __restrict__ out,
                             int Hd, int Wd, int r, float thresh) {
    int idx = blockIdx.x * 256 + threadIdx.x;
    int tot = BB * Hd * Wd;
    if (idx >= tot) return;
    int x = idx % Wd; int y = (idx / Wd) % Hd; int b = idx / (Wd * Hd);
    const float* base = in + (size_t)b * Hd * Wd;
    float s = 0.f;
    for (int dy = -r; dy <= r; ++dy) {
        int yy = y + dy; if (yy < 0 || yy >= Hd) continue;
        for (int dx = -r; dx <= r; ++dx) {
            if (dx * dx + dy * dy > r * r) continue;
            int xx = x + dx; if (xx < 0 || xx >= Wd) continue;
            s += base[yy * Wd + xx];
        }
    }
    out[idx] = (s > thresh) ? 1.f : 0.f;
}

__global__ void pad3_kernel(const float* __restrict__ in, float* __restrict__ out) {
    int idx = blockIdx.x * 256 + threadIdx.x;
    int tot = BB * 134 * 134; if (idx >= tot) return;
    int x = idx % 134; int y = (idx / 134) % 134; int b = idx / (134 * 134);
    float v = 0.f;
    int xs = x - 3, ys = y - 3;
    if (xs >= 0 && xs < 128 && ys >= 0 && ys < 128)
        v = in[((size_t)b * 128 + ys) * 128 + xs];
    out[idx] = v;
}

__global__ void vfinal_kernel(const float* __restrict__ in, float* __restrict__ V) {
    int idx = blockIdx.x * 256 + threadIdx.x; // B*HWSZ
    if (idx >= BB * HWSZ) return;
    int x = idx & 127; int y = (idx >> 7) & 127; int b = idx >> 14;
    V[idx] = 1.f - in[((size_t)b * 134 + y + 3) * 134 + (x + 3)];
}

// ---------------------------------------------------------------- launch
extern "C" void kernel_launch(void* const* d_in, const int* in_sizes, int n_in,
                              void* d_out, int out_size, void* d_ws, size_t ws_size,
                              hipStream_t stream) {
    const float* x_p   = (const float*)d_in[0];
    const float* x_c   = (const float*)d_in[1];
    const float* pa_w1 = (const float*)d_in[2];
    const float* pa_b1 = (const float*)d_in[3];
    const float* pa_w2 = (const float*)d_in[4];
    const float* pa_b2 = (const float*)d_in[5];
    const float* pa_wc = (const float*)d_in[6];
    const float* pa_bc = (const float*)d_in[7];
    const float* ca_aw1 = (const float*)d_in[8];
    const float* ca_ab1 = (const float*)d_in[9];
    const float* ca_aw2 = (const float*)d_in[10];
    const float* ca_ab2 = (const float*)d_in[11];
    const float* ca_mw1 = (const float*)d_in[12];
    const float* ca_mb1 = (const float*)d_in[13];
    const float* ca_mw2 = (const float*)d_in[14];
    const float* ca_mb2 = (const float*)d_in[15];
    const float* b1_w  = (const float*)d_in[16];
    const float* b1_b  = (const float*)d_in[17];
    const float* b2_w  = (const float*)d_in[18];
    const float* b2_b  = (const float*)d_in[19];
    const float* b3_w  = (const float*)d_in[20];
    const float* b3_b  = (const float*)d_in[21];
    const float* fus_w = (const float*)d_in[22];
    const float* fus_b = (const float*)d_in[23];
    float* out = (float*)d_out;

    char* wsb = (char*)d_ws;
    bf16* A  = (bf16*)wsb;                    // NTOT bf16 (64 MiB)
    bf16* Bb = (bf16*)(wsb + NTOT * 2);       // NTOT bf16 (64 MiB)
    float* smalls = (float*)(wsb + NTOT * 4);
    float* avgv = smalls;                     // 2048
    float* maxv = smalls + 2048;              // 2048
    float* gate = smalls + 4096;              // 2048
    float* mph0 = smalls + 6144;              // 143648
    float* mph1 = mph0 + 143648;              // 143648
    float* Vfin = mph1 + 143648;              // 131072  (ends at 424512 floats)
    // prepped weights: 1179648 shorts (2.25 MiB), 16B-aligned
    short* Wprep = (short*)(wsb + NTOT * 4 + 1703936);
    const short* Wp_paw1 = Wprep + 0;
    const short* Wp_paw2 = Wprep + 131072;
    const short* Wp_pawc = Wprep + 262144;
    const short* Wp_b1   = Wprep + 524288;
    const short* Wp_b2   = Wprep + 655360;
    const short* Wp_b3   = Wprep + 786432;
    const short* Wp_fus  = Wprep + 917504;
    bf16* D1 = (bf16*)d_out;                  // NTOT bf16
    bf16* D2 = D1 + NTOT;                     // NTOT bf16
    bf16* Mbuf = D1;                          // 16.7M bf16 (32 MiB)

    dim3 cgrid(HWSZ / BMP, CC / BNO, BB);     // (128, 2, 8)
    const int TPB = 256;

    // --- weight prep (once per launch, ~2.3 MiB) ---
    prep_w_kernel<<<2304, TPB, 0, stream>>>(pa_w1, pa_w2, pa_wc, b1_w, b2_w, b3_w, fus_w, Wprep);

    // --- PALayer ---
    pool3_kernel<<<NTOT / 8 / 256, TPB, 0, stream>>>(x_p, A, Bb); // y1->A, y2->Bb
    conv1x1_kernel<EPI_RELU, false, false, false, bf16, bf16, bf16, bf16>
        <<<cgrid, TPB, 0, stream>>>(D1, A, nullptr, Wp_paw1, pa_b1,
                                    nullptr, nullptr, nullptr, nullptr, 0);       // z1->D1
    conv1x1_kernel<EPI_ADDAUX, false, false, false, bf16, bf16, bf16, bf16>
        <<<cgrid, TPB, 0, stream>>>(D2, D1, nullptr, Wp_paw2, pa_b2,
                                    A, nullptr, nullptr, nullptr, 0);             // u=conv(z1)+y1 ->D2
    conv1x1_kernel<EPI_RELU, false, false, false, bf16, bf16, bf16, bf16>
        <<<cgrid, TPB, 0, stream>>>(A, Bb, nullptr, Wp_paw1, pa_b1,
                                    nullptr, nullptr, nullptr, nullptr, 0);       // z2->A
    conv1x1_kernel<EPI_ADDAUX, false, false, false, bf16, bf16, bf16, bf16>
        <<<cgrid, TPB, 0, stream>>>(D1, A, nullptr, Wp_paw2, pa_b2,
                                    Bb, nullptr, nullptr, nullptr, 0);            // v=conv(z2)+y2 ->D1
    conv1x1_kernel<EPI_SIGMUL, true, false, false, bf16, bf16, float, bf16>
        <<<cgrid, TPB, 0, stream>>>(A, D2, D1, Wp_pawc, pa_bc,
                                    x_p, nullptr, nullptr, nullptr, 0);           // buffer_p->A

    // --- CALayer gate ---
    ca_reduce_kernel<<<BB * CC, TPB, 0, stream>>>(x_c, avgv, maxv);
    ca_mlp_kernel<<<BB, TPB, 0, stream>>>(avgv, maxv, ca_aw1, ca_ab1, ca_aw2, ca_ab2,
                                          ca_mw1, ca_mb1, ca_mw2, ca_mb2, gate);

    // --- Q/S projections ---
    conv1x1_kernel<EPI_NONE, false, false, false, bf16, bf16, bf16, bf16>
        <<<cgrid, TPB, 0, stream>>>(Bb, A, nullptr, Wp_b1, b1_b,
                                    nullptr, nullptr, nullptr, nullptr, 0);       // Q1->Bb
    conv1x1_kernel<EPI_NONE, false, false, false, bf16, bf16, bf16, bf16>
        <<<cgrid, TPB, 0, stream>>>(D1, A, nullptr, Wp_b2, b2_b,
                                    nullptr, nullptr, nullptr, nullptr, 0);       // S2->D1
    conv1x1_kernel<EPI_NONE, false, true, false, float, float, float, bf16>
        <<<cgrid, TPB, 0, stream>>>(A, x_c, nullptr, Wp_b1, b1_b,
                                    nullptr, gate, nullptr, nullptr, 0);          // Q2->A
    conv1x1_kernel<EPI_NONE, false, true, false, float, float, float, bf16>
        <<<cgrid, TPB, 0, stream>>>(D2, x_c, nullptr, Wp_b2, b2_b,
                                    nullptr, gate, nullptr, nullptr, 0);          // S1->D2

    // --- attention softmaxes ---
    attn_kernel<false><<<BB * HH, TPB, 0, stream>>>(A, D1, nullptr, mph0);  // M_p_to_c colsum -> m0
    attn_kernel<true><<<BB * HH, TPB, 0, stream>>>(Bb, D2, Mbuf, nullptr);  // M_c_to_p -> Mbuf (D1)

    // --- v3 ---
    conv1x1_kernel<EPI_NONE, false, false, false, float, float, float, bf16>
        <<<cgrid, TPB, 0, stream>>>(A, x_c, nullptr, Wp_b3, b3_b,
                                    nullptr, nullptr, nullptr, nullptr, 0);       // v3->A

    // --- morphology (tiny) ---
    morph_kernel<<<512, TPB, 0, stream>>>(mph0, mph1, 128, 128, 2, 12.5f);
    morph_kernel<<<512, TPB, 0, stream>>>(mph1, mph0, 128, 128, 2, 0.5f);
    morph_kernel<<<512, TPB, 0, stream>>>(mph0, mph1, 128, 128, 1, 0.5f);
    morph_kernel<<<512, TPB, 0, stream>>>(mph1, mph0, 128, 128, 1, 4.5f);
    pad3_kernel<<<562, TPB, 0, stream>>>(mph0, mph1);
    morph_kernel<<<562, TPB, 0, stream>>>(mph1, mph0, 134, 134, 3, 0.5f);
    morph_kernel<<<562, TPB, 0, stream>>>(mph0, mph1, 134, 134, 3, 28.5f);
    vfinal_kernel<<<512, TPB, 0, stream>>>(mph1, Vfin);

    // --- attend + fusion ---
    attn_apply_kernel<<<dim3(BB * HH, 2), TPB, 0, stream>>>(Mbuf, A, Bb);
    conv1x1_kernel<EPI_NONE, true, false, true, bf16, float, float, float>
        <<<cgrid, TPB, 0, stream>>>(out, Bb, x_p, Wp_fus, fus_b,
                                    nullptr, nullptr, Vfin, fus_w + 512, 513);    // final -> d_out fp32
}

// Round 4
// 1404.180 us; speedup vs baseline: 2.9106x; 1.0067x over previous
//
#include <hip/hip_runtime.h>
#include <hip/hip_bf16.h>
#include <math.h>

#define BB 8
#define CC 256
#define HH 128
#define WW 128
#define HWSZ (HH*WW)              // 16384
#define NTOT ((size_t)BB*CC*HWSZ) // 33554432 elements

typedef __hip_bfloat16 bf16;
typedef __attribute__((ext_vector_type(8))) short short8v; // 8 bf16 = 4 VGPR (MFMA A/B frag)
typedef __attribute__((ext_vector_type(4))) float f32x4;   // MFMA C/D frag

__device__ __forceinline__ float ldf(const float* p) { return *p; }
__device__ __forceinline__ float ldf(const bf16* p) { return __bfloat162float(*p); }
__device__ __forceinline__ void stf(float* p, float v) { *p = v; }
__device__ __forceinline__ void stf(bf16* p, float v) { *p = __float2bfloat16(v); }

union bfu { bf16 b; unsigned short u; };
__device__ __forceinline__ unsigned short f2bf_bits(float v) { bfu c; c.b = __float2bfloat16(v); return c.u; }
__device__ __forceinline__ float bfbits2f(unsigned short u) { bfu c; c.u = u; return __bfloat162float(c.b); }
__device__ __forceinline__ unsigned pk2(float a, float b) {
    return (unsigned)f2bf_bits(a) | ((unsigned)f2bf_bits(b) << 16);
}

// global->LDS direct DMA, 16B per lane. LDS dest = wave-uniform base + lane*16.
__device__ __forceinline__ void gld16(const void* g, void* l) {
    __builtin_amdgcn_global_load_lds(
        (const __attribute__((address_space(1))) unsigned int*)(uintptr_t)g,
        (__attribute__((address_space(3))) unsigned int*)(uintptr_t)l, 16, 0, 0);
}

// MF format: bf16 tensor [b][px][256], channel position within each 64-tile:
//   P(c) = ((c>>5)&1)*32 + ((c>>2)&3)*8 + ((c>>4)&1)*4 + (c&3), XOR'd by (px&7)<<3.
// This IS the MFMA-fragment LDS image: conv/attn stage tiles with pure DMA.
__device__ __forceinline__ int mf_p64(int c) {   // c in [0,64), 4-aligned pieces stay consecutive
    return ((c >> 5) & 1) * 32 + ((c >> 2) & 3) * 8 + ((c >> 4) & 1) * 4 + (c & 3);
}

// ---------------------------------------------------------------- pool 3x3 -> MF
// block: 8 channels x 256 pixels. Phase 1: thread = 8px x 1c (separable window).
// Phase 2: LDS transpose, thread = 1px x 8c, two 8B MF stores per tensor.
__global__ __launch_bounds__(256) void pool3_mf_kernel(const float* __restrict__ x,
                                                       bf16* __restrict__ yavg,
                                                       bf16* __restrict__ ymax) {
    int bi = blockIdx.x;          // 8b * 32cb * 64pxb = 16384
    int pxb = bi & 63;
    int cb  = (bi >> 6) & 31;
    int b   = bi >> 11;
    int tid = threadIdx.x;
    int cl  = tid >> 5;           // 0..7
    int pxl = (tid & 31) * 8;     // 0..248
    int c   = cb * 8 + cl;
    int px  = pxb * 256 + pxl;
    int h   = px >> 7, w0 = px & 127;
    const float* base = x + ((size_t)b * 256 + c) * HWSZ;
    float ts[8], tm[8];
#pragma unroll
    for (int i = 0; i < 8; ++i) { ts[i] = 0.f; tm[i] = -INFINITY; }
#pragma unroll
    for (int dy = -1; dy <= 1; ++dy) {
        int hh = h + dy;
        if (hh < 0 || hh >= HH) continue;
        const float* rp = base + hh * WW + w0;
        float4 v0 = *(const float4*)rp;
        float4 v1 = *(const float4*)(rp + 4);
        float s9[10], m9[10];
        s9[1] = v0.x; s9[2] = v0.y; s9[3] = v0.z; s9[4] = v0.w;
        s9[5] = v1.x; s9[6] = v1.y; s9[7] = v1.z; s9[8] = v1.w;
#pragma unroll
        for (int i = 1; i < 9; ++i) m9[i] = s9[i];
        if (w0 > 0)      { float L = rp[-1]; s9[0] = L; m9[0] = L; }
        else             { s9[0] = 0.f; m9[0] = -INFINITY; }
        if (w0 < WW - 8) { float R = rp[8]; s9[9] = R; m9[9] = R; }
        else             { s9[9] = 0.f; m9[9] = -INFINITY; }
#pragma unroll
        for (int i = 0; i < 8; ++i) {
            ts[i] += s9[i] + s9[i + 1] + s9[i + 2];
            tm[i] = fmaxf(tm[i], fmaxf(m9[i], fmaxf(m9[i + 1], m9[i + 2])));
        }
    }
    __shared__ short La[8][256];
    __shared__ short Lm[8][256];
    {
        uint4 ua, um;
        ua.x = pk2(ts[0]*(1.f/9.f), ts[1]*(1.f/9.f));
        ua.y = pk2(ts[2]*(1.f/9.f), ts[3]*(1.f/9.f));
        ua.z = pk2(ts[4]*(1.f/9.f), ts[5]*(1.f/9.f));
        ua.w = pk2(ts[6]*(1.f/9.f), ts[7]*(1.f/9.f));
        um.x = pk2(tm[0], tm[1]); um.y = pk2(tm[2], tm[3]);
        um.z = pk2(tm[4], tm[5]); um.w = pk2(tm[6], tm[7]);
        *(uint4*)&La[cl][pxl] = ua;
        *(uint4*)&Lm[cl][pxl] = um;
    }
    __syncthreads();
    int pg = pxb * 256 + tid;                 // this thread's pixel
    unsigned short a8[8], m8[8];
#pragma unroll
    for (int i = 0; i < 8; ++i) { a8[i] = (unsigned short)La[i][tid]; m8[i] = (unsigned short)Lm[i][tid]; }
    size_t rowb = ((size_t)b * 16384 + pg) * 256;
    int swz = (pg & 7) << 3;
    int c0 = cb * 8;
#pragma unroll
    for (int q = 0; q < 2; ++q) {
        int cc = c0 + q * 4;
        int col = (cc >> 6) * 64 + (mf_p64(cc & 63) ^ swz);
        uint2 ua, um;
        ua.x = (unsigned)a8[q*4+0] | ((unsigned)a8[q*4+1] << 16);
        ua.y = (unsigned)a8[q*4+2] | ((unsigned)a8[q*4+3] << 16);
        um.x = (unsigned)m8[q*4+0] | ((unsigned)m8[q*4+1] << 16);
        um.y = (unsigned)m8[q*4+2] | ((unsigned)m8[q*4+3] << 16);
        *(uint2*)((short*)yavg + rowb + col) = ua;
        *(uint2*)((short*)ymax + rowb + col) = um;
    }
}

// ---------------------------------------------------------------- x_c * gate -> MF
__global__ __launch_bounds__(256) void xcs_prep_kernel(const float* __restrict__ xc,
                                                       const float* __restrict__ gate,
                                                       bf16* __restrict__ dst) {
    int bi = blockIdx.x;          // 16384
    int pxb = bi & 63;
    int cb  = (bi >> 6) & 31;
    int b   = bi >> 11;
    int tid = threadIdx.x;
    int cl  = tid >> 5;
    int pxl = (tid & 31) * 8;
    int c   = cb * 8 + cl;
    int px  = pxb * 256 + pxl;
    const float* rp = xc + ((size_t)b * 256 + c) * HWSZ + px;
    float g = gate[b * 256 + c];
    float4 v0 = *(const float4*)rp;
    float4 v1 = *(const float4*)(rp + 4);
    __shared__ short L[8][256];
    uint4 u;
    u.x = pk2(v0.x * g, v0.y * g); u.y = pk2(v0.z * g, v0.w * g);
    u.z = pk2(v1.x * g, v1.y * g); u.w = pk2(v1.z * g, v1.w * g);
    *(uint4*)&L[cl][pxl] = u;
    __syncthreads();
    int pg = pxb * 256 + tid;
    unsigned short a8[8];
#pragma unroll
    for (int i = 0; i < 8; ++i) a8[i] = (unsigned short)L[i][tid];
    size_t rowb = ((size_t)b * 16384 + pg) * 256;
    int swz = (pg & 7) << 3;
    int c0 = cb * 8;
#pragma unroll
    for (int q = 0; q < 2; ++q) {
        int cc = c0 + q * 4;
        int col = (cc >> 6) * 64 + (mf_p64(cc & 63) ^ swz);
        uint2 ua;
        ua.x = (unsigned)a8[q*4+0] | ((unsigned)a8[q*4+1] << 16);
        ua.y = (unsigned)a8[q*4+2] | ((unsigned)a8[q*4+3] << 16);
        *(uint2*)((short*)dst + rowb + col) = ua;
    }
}

// ---------------------------------------------------------------- weight prep
// fp32 -> bf16 hi|lo planes, permuted+swizzled LDS tile image (unchanged layout).
__global__ __launch_bounds__(256) void prep_w_kernel(
    const float* __restrict__ w0, const float* __restrict__ w1,
    const float* __restrict__ w2, const float* __restrict__ w3,
    const float* __restrict__ w4, const float* __restrict__ w5,
    const float* __restrict__ w6, short* __restrict__ dst)
{
    int gid = blockIdx.x * 256 + threadIdx.x;  // 0..589823
    const float* src; int K, WS, local; size_t dofs;
    if (gid < 65536)       { src = w0; K = 256; WS = 256; dofs = 0;      local = gid; }
    else if (gid < 131072) { src = w1; K = 256; WS = 256; dofs = 131072; local = gid - 65536; }
    else if (gid < 262144) { src = w2; K = 512; WS = 512; dofs = 262144; local = gid - 131072; }
    else if (gid < 327680) { src = w3; K = 256; WS = 256; dofs = 524288; local = gid - 262144; }
    else if (gid < 393216) { src = w4; K = 256; WS = 256; dofs = 655360; local = gid - 327680; }
    else if (gid < 458752) { src = w5; K = 256; WS = 256; dofs = 786432; local = gid - 393216; }
    else                   { src = w6; K = 512; WS = 513; dofs = 917504; local = gid - 458752; }
    int o = (K == 256) ? (local >> 8) : (local >> 9);
    int k = local & (K - 1);
    int kt = k >> 6, k6 = k & 63;
    int pos = mf_p64(k6) ^ ((o & 7) << 3);
    size_t off = dofs + (size_t)(o >> 7) * K * 128 + (size_t)kt * 8192 + (size_t)(o & 127) * 64 + pos;
    float v = src[(size_t)o * WS + k];
    unsigned short hb = f2bf_bits(v);
    dst[off] = (short)hb;
    dst[off + (size_t)256 * K] = (short)f2bf_bits(v - bfbits2f(hb));
}

// ---------------------------------------------------------------- conv1x1 MFMA (MF in / MF out)
// A = W [o][k] (hi+lo), B = X [px][k]. Both staged via global_load_lds DMA.
// D: col = px (lane&15 group), row = o (4 consecutive per lane).
#define EPI_NONE   0
#define EPI_RELU   1
#define EPI_ADDAUX 2
#define EPI_SIGMUL 3

__device__ __forceinline__ void load4f(const bf16* p, float* v) {
    ushort4 u = *(const ushort4*)p;
    v[0] = bfbits2f(u.x); v[1] = bfbits2f(u.y); v[2] = bfbits2f(u.z); v[3] = bfbits2f(u.w);
}
__device__ __forceinline__ void load4f(const float* p, float* v) {
    float4 u = *(const float4*)p;
    v[0] = u.x; v[1] = u.y; v[2] = u.z; v[3] = u.w;
}
__device__ __forceinline__ void store4(bf16* p, const float* v) {
    uint2 u; u.x = pk2(v[0], v[1]); u.y = pk2(v[2], v[3]);
    *(uint2*)p = u;
}
__device__ __forceinline__ void store4(float* p, const float* v) {
    *(float4*)p = make_float4(v[0], v[1], v[2], v[3]);
}

template<int MODE, bool TWO_IN, class TAUX>
__global__ __launch_bounds__(256) void conv_mf_kernel(
    bf16* __restrict__ out,
    const bf16* __restrict__ in1,    // MF
    const bf16* __restrict__ in2,    // MF (TWO_IN)
    const short* __restrict__ Wp,    // prepped hi|lo tile image
    const float* __restrict__ bias,
    const TAUX* __restrict__ aux)    // bf16: MF-addressed; float: NCHW (SIGMUL x_p)
{
    const int K = TWO_IN ? 512 : 256;
    __shared__ __align__(16) short Xs[128 * 64];
    __shared__ __align__(16) short Wh[128 * 64];
    __shared__ __align__(16) short Wl[128 * 64];
    const int tid = threadIdx.x;
    const int b = blockIdx.z;
    const int p0 = blockIdx.x * 128;
    const int o0 = blockIdx.y * 128;
    const int lane = tid & 63, wave = tid >> 6;
    const int wr = wave >> 1, wc = wave & 1;       // wr: o-half, wc: px-half
    const int lrow = lane & 15, lg = lane >> 4;
    const int sA = (lrow & 7) << 3;

    f32x4 acc[4][4];   // [mi over o][ni over px]
#pragma unroll
    for (int mi = 0; mi < 4; ++mi)
#pragma unroll
        for (int ni = 0; ni < 4; ++ni) acc[mi][ni] = (f32x4)(0.f);

    for (int kt = 0; kt < K / 64; ++kt) {
        // W DMA: 16KB hi + 16KB lo
        {
            const short* gWh = Wp + (size_t)(o0 >> 7) * K * 128 + (size_t)kt * 8192;
            const short* gWl = gWh + (size_t)256 * K;
            const int wofs = wave * 4096;
            const int lb = lane * 16;
#pragma unroll
            for (int q = 0; q < 4; ++q) {
                gld16((const char*)gWh + wofs + q * 1024 + lb, (char*)Wh + wofs + q * 1024);
                gld16((const char*)gWl + wofs + q * 1024 + lb, (char*)Wl + wofs + q * 1024);
            }
        }
        // X DMA: 16KB (128 px rows x 128B k-segment)
        {
            const bf16* src = (TWO_IN && kt >= 4) ? in2 : in1;
            const int ktl = (TWO_IN && kt >= 4) ? kt - 4 : kt;
            const char* gX = (const char*)src + (((size_t)b * 16384 + p0) * 256 + ktl * 64) * 2;
            const int lofs = (lane >> 3) * 512 + (lane & 7) * 16;
#pragma unroll
            for (int q = 0; q < 4; ++q) {
                gld16(gX + (size_t)(wave * 32 + q * 8) * 512 + lofs,
                      (char*)Xs + wave * 4096 + q * 1024);
            }
        }
        __syncthreads();
#pragma unroll
        for (int kk = 0; kk < 2; ++kk) {
            const int kofs = (kk * 32 + lg * 8) ^ sA;
            short8v aw[4], al[4], bx[4];
#pragma unroll
            for (int mi = 0; mi < 4; ++mi) {
                aw[mi] = *(const short8v*)&Wh[(wr * 64 + mi * 16 + lrow) * 64 + kofs];
                al[mi] = *(const short8v*)&Wl[(wr * 64 + mi * 16 + lrow) * 64 + kofs];
            }
#pragma unroll
            for (int ni = 0; ni < 4; ++ni)
                bx[ni] = *(const short8v*)&Xs[(wc * 64 + ni * 16 + lrow) * 64 + kofs];
#pragma unroll
            for (int mi = 0; mi < 4; ++mi)
#pragma unroll
                for (int ni = 0; ni < 4; ++ni)
                    acc[mi][ni] = __builtin_amdgcn_mfma_f32_16x16x32_bf16(aw[mi], bx[ni], acc[mi][ni], 0, 0, 0);
#pragma unroll
            for (int mi = 0; mi < 4; ++mi)
#pragma unroll
                for (int ni = 0; ni < 4; ++ni)
                    acc[mi][ni] = __builtin_amdgcn_mfma_f32_16x16x32_bf16(al[mi], bx[ni], acc[mi][ni], 0, 0, 0);
        }
        __syncthreads();
    }

    // epilogue: lane holds 4 consecutive o at fixed px per frag -> 8B MF stores
#pragma unroll
    for (int mi = 0; mi < 4; ++mi) {
        const int ob = o0 + wr * 64 + mi * 16 + lg * 4;
        float b4[4];
        load4f(&bias[ob], b4);
        const int pcol = (ob >> 6) * 64 + mf_p64(ob & 63);   // 4-aligned -> +r stays consecutive
#pragma unroll
        for (int ni = 0; ni < 4; ++ni) {
            const int px = p0 + wc * 64 + ni * 16 + lrow;
            const size_t rowb = ((size_t)b * 16384 + px) * 256;
            const size_t ad = rowb + ((size_t)pcol ^ (size_t)((px & 7) << 3));
            float vals[4];
            float auxv[4];
            if (MODE == EPI_ADDAUX) load4f((const bf16*)aux + ad, auxv);
#pragma unroll
            for (int r = 0; r < 4; ++r) {
                float val = acc[mi][ni][r] + b4[r];
                if (MODE == EPI_RELU) val = fmaxf(val, 0.f);
                else if (MODE == EPI_ADDAUX) val += auxv[r];
                else if (MODE == EPI_SIGMUL) {
                    float xp = ((const float*)aux)[((size_t)b * 256 + ob + r) * HWSZ + px];
                    val = (1.f / (1.f + __expf(-val))) * xp;
                }
                vals[r] = val;
            }
            store4((bf16*)out + ad, vals);
        }
    }
}

// ---------------------------------------------------------------- conv1x1 (NCHW out, scalar-staged X)
// retained for v3 (fp32 NCHW in -> NCHW bf16 out) and fusion (NCHW in -> fp32 out).
template<bool SC, class T>
__device__ __forceinline__ unsigned short ld_bits(const T* p, float s);
template<> __device__ __forceinline__ unsigned short ld_bits<false, bf16>(const bf16* p, float) {
    bfu c; c.b = *p; return c.u;
}
template<> __device__ __forceinline__ unsigned short ld_bits<false, float>(const float* p, float) {
    return f2bf_bits(*p);
}

template<bool SC, class T>
__device__ __forceinline__ void stage_X(short* __restrict__ Xs,
                                        const T* __restrict__ in,
                                        const float* __restrict__ scale,
                                        int b, int cbase, size_t pbase, int tid)
{
    const int xp  = tid & 127;
    const int xkh = (tid >> 7) * 32;
    const T* src = in + ((size_t)b * 256 + cbase + xkh) * HWSZ + pbase + xp;
    const int swz = (xp & 7) << 3;
    short* dst = Xs + xp * 64;
#pragma unroll
    for (int g = 0; g < 4; ++g) {
        unsigned short u[8];
#pragma unroll
        for (int j = 0; j < 8; ++j) {
            int k5 = (j >> 2) * 16 + g * 4 + (j & 3);
            u[j] = ld_bits<SC, T>(src + (size_t)k5 * HWSZ, 1.f);
        }
        uint4 wv;
        wv.x = (unsigned)u[0] | ((unsigned)u[1] << 16);
        wv.y = (unsigned)u[2] | ((unsigned)u[3] << 16);
        wv.z = (unsigned)u[4] | ((unsigned)u[5] << 16);
        wv.w = (unsigned)u[6] | ((unsigned)u[7] << 16);
        *(uint4*)(dst + ((xkh + g * 8) ^ swz)) = wv;
    }
}

template<int MODE, bool TWO_IN, bool HAS_V, class TIN1, class TIN2, class TOUT>
__global__ __launch_bounds__(256) void conv1x1_kernel(
    TOUT* __restrict__ out,
    const TIN1* __restrict__ in1,
    const TIN2* __restrict__ in2,
    const short* __restrict__ Wp,
    const float* __restrict__ bias,
    const float* __restrict__ vvec,
    const float* __restrict__ vw, int vws)
{
    const int K = TWO_IN ? 512 : 256;
    __shared__ __align__(16) short Xs[128 * 64];
    __shared__ __align__(16) short Wh[128 * 64];
    __shared__ __align__(16) short Wl[128 * 64];
    const int tid = threadIdx.x;
    const int b = blockIdx.z;
    const size_t p0 = (size_t)blockIdx.x * 128;
    const int o0 = blockIdx.y * 128;
    const int lane = tid & 63, wave = tid >> 6;
    const int wr = wave >> 1, wc = wave & 1;
    const int lrow = lane & 15, lg = lane >> 4;
    const int sA = (lrow & 7) << 3;

    f32x4 acc[4][4];
#pragma unroll
    for (int mi = 0; mi < 4; ++mi)
#pragma unroll
        for (int ni = 0; ni < 4; ++ni) acc[mi][ni] = (f32x4)(0.f);

    for (int kt = 0; kt < K / 64; ++kt) {
        const int k0 = kt * 64;
        {
            const short* gWh = Wp + (size_t)(o0 >> 7) * K * 128 + (size_t)kt * 8192;
            const short* gWl = gWh + (size_t)256 * K;
            const int wofs = wave * 4096;
            const int lb = lane * 16;
#pragma unroll
            for (int q = 0; q < 4; ++q) {
                gld16((const char*)gWh + wofs + q * 1024 + lb, (char*)Wh + wofs + q * 1024);
                gld16((const char*)gWl + wofs + q * 1024 + lb, (char*)Wl + wofs + q * 1024);
            }
        }
        if (TWO_IN && k0 >= 256)
            stage_X<false, TIN2>(Xs, in2, nullptr, b, k0 - 256, p0, tid);
        else
            stage_X<false, TIN1>(Xs, in1, nullptr, b, k0, p0, tid);
        __syncthreads();
#pragma unroll
        for (int kk = 0; kk < 2; ++kk) {
            const int kofs = (kk * 32 + lg * 8) ^ sA;
            short8v af[4], bh[4], bl[4];
#pragma unroll
            for (int mi = 0; mi < 4; ++mi)
                af[mi] = *(const short8v*)&Xs[(wr * 64 + mi * 16 + lrow) * 64 + kofs];
#pragma unroll
            for (int ni = 0; ni < 4; ++ni) {
                bh[ni] = *(const short8v*)&Wh[(wc * 64 + ni * 16 + lrow) * 64 + kofs];
                bl[ni] = *(const short8v*)&Wl[(wc * 64 + ni * 16 + lrow) * 64 + kofs];
            }
#pragma unroll
            for (int mi = 0; mi < 4; ++mi)
#pragma unroll
                for (int ni = 0; ni < 4; ++ni)
                    acc[mi][ni] = __builtin_amdgcn_mfma_f32_16x16x32_bf16(af[mi], bh[ni], acc[mi][ni], 0, 0, 0);
#pragma unroll
            for (int mi = 0; mi < 4; ++mi)
#pragma unroll
                for (int ni = 0; ni < 4; ++ni)
                    acc[mi][ni] = __builtin_amdgcn_mfma_f32_16x16x32_bf16(af[mi], bl[ni], acc[mi][ni], 0, 0, 0);
        }
        __syncthreads();
    }

#pragma unroll
    for (int ni = 0; ni < 4; ++ni) {
        const int o = o0 + wc * 64 + ni * 16 + lrow;
        const float bs = bias[o];
        const float vwo = HAS_V ? vw[(size_t)o * vws] : 0.f;
#pragma unroll
        for (int mi = 0; mi < 4; ++mi) {
            const size_t p = p0 + wr * 64 + mi * 16 + lg * 4;
            const size_t oidx = ((size_t)b * CC + o) * HWSZ + p;
            float vv[4];
            if (HAS_V) load4f(&vvec[(size_t)b * HWSZ + p], vv);
            float vals[4];
#pragma unroll
            for (int r = 0; r < 4; ++r) {
                float val = acc[mi][ni][r] + bs;
                if (HAS_V) val += vwo * vv[r];
                vals[r] = val;
            }
            store4(&out[oidx], vals);
        }
    }
}

// ---------------------------------------------------------------- CA reduce
__global__ __launch_bounds__(256) void ca_reduce_kernel(const float* __restrict__ xc,
                                                        float* __restrict__ avgv,
                                                        float* __restrict__ maxv) {
    int bc = blockIdx.x; // 0..2047
    const float4* base = (const float4*)(xc + (size_t)bc * HWSZ);
    float s = 0.f, mx = -INFINITY;
    for (int i = threadIdx.x; i < HWSZ / 4; i += 256) {
        float4 v = base[i];
        s += v.x + v.y + v.z + v.w;
        mx = fmaxf(mx, fmaxf(fmaxf(v.x, v.y), fmaxf(v.z, v.w)));
    }
    for (int off = 32; off; off >>= 1) {
        s += __shfl_down(s, off);
        mx = fmaxf(mx, __shfl_down(mx, off));
    }
    __shared__ float ss[4], sm[4];
    int wid = threadIdx.x >> 6, lane = threadIdx.x & 63;
    if (lane == 0) { ss[wid] = s; sm[wid] = mx; }
    __syncthreads();
    if (threadIdx.x == 0) {
        float S = ss[0] + ss[1] + ss[2] + ss[3];
        float M = fmaxf(fmaxf(sm[0], sm[1]), fmaxf(sm[2], sm[3]));
        avgv[bc] = S * (1.f / HWSZ);
        maxv[bc] = M;
    }
}

// ---------------------------------------------------------------- CA MLP (tiny)
__global__ __launch_bounds__(256) void ca_mlp_kernel(
    const float* __restrict__ avgv, const float* __restrict__ maxv,
    const float* __restrict__ aw1, const float* __restrict__ ab1,
    const float* __restrict__ aw2, const float* __restrict__ ab2,
    const float* __restrict__ mw1, const float* __restrict__ mb1,
    const float* __restrict__ mw2, const float* __restrict__ mb2,
    float* __restrict__ gate) {
    int b = blockIdx.x;
    __shared__ float av[256], mv[256], ha[16], hm[16];
    int t = threadIdx.x;
    av[t] = avgv[b * 256 + t];
    mv[t] = maxv[b * 256 + t];
    __syncthreads();
    if (t < 16) {
        float s = ab1[t];
        for (int i = 0; i < 256; ++i) s += aw1[t * 256 + i] * av[i];
        ha[t] = fmaxf(s, 0.f);
    } else if (t < 32) {
        int r = t - 16;
        float s = mb1[r];
        for (int i = 0; i < 256; ++i) s += mw1[r * 256 + i] * mv[i];
        hm[r] = fmaxf(s, 0.f);
    }
    __syncthreads();
    float ya = ab2[t], ym = mb2[t];
    for (int r = 0; r < 16; ++r) {
        ya += aw2[t * 16 + r] * ha[r];
        ym += mw2[t * 16 + r] * hm[r];
    }
    float g = ya + ym;
    gate[b * 256 + t] = 1.f / (1.f + __expf(-g));
}

// ---------------------------------------------------------------- attention logits+softmax (MFMA, MF in)
// Q,S in MF format -> pure DMA staging. STORE_M writes M in MF-j format for DMA re-read.
template<bool STORE_M>
__global__ __launch_bounds__(256) void attn_kernel(
    const bf16* __restrict__ Q, const bf16* __restrict__ S,
    bf16* __restrict__ Mout, float* __restrict__ m0out)
{
    int bh = blockIdx.x; int b = bh >> 7, h = bh & 127;
    const char* Qb = (const char*)Q + ((size_t)(b * 16384 + h * 128)) * 512;
    const char* Sb = (const char*)S + ((size_t)(b * 16384 + h * 128)) * 512;
    __shared__ __align__(16) short Qs[128 * 64];
    __shared__ __align__(16) short Ss[128 * 64];
    const int tid = threadIdx.x;
    const int lane = tid & 63, wave = tid >> 6;
    const int lrow = lane & 15, lg = lane >> 4;
    const int sA = (lrow & 7) << 3;

    f32x4 acc[2][8];
#pragma unroll
    for (int mi = 0; mi < 2; ++mi)
#pragma unroll
        for (int ni = 0; ni < 8; ++ni) acc[mi][ni] = (f32x4)(0.f);

    for (int kt = 0; kt < 4; ++kt) {
        const int lofs = (lane >> 3) * 512 + (lane & 7) * 16 + kt * 128;
#pragma unroll
        for (int q = 0; q < 4; ++q) {
            gld16(Qb + (size_t)(wave * 32 + q * 8) * 512 + lofs, (char*)Qs + wave * 4096 + q * 1024);
            gld16(Sb + (size_t)(wave * 32 + q * 8) * 512 + lofs, (char*)Ss + wave * 4096 + q * 1024);
        }
        __syncthreads();
#pragma unroll
        for (int kk = 0; kk < 2; ++kk) {
            const int kofs = (kk * 32 + lg * 8) ^ sA;
            short8v qa[2], sv[8];
#pragma unroll
            for (int mi = 0; mi < 2; ++mi)
                qa[mi] = *(const short8v*)&Qs[(wave * 32 + mi * 16 + lrow) * 64 + kofs];
#pragma unroll
            for (int ni = 0; ni < 8; ++ni)
                sv[ni] = *(const short8v*)&Ss[(ni * 16 + lrow) * 64 + kofs];
#pragma unroll
            for (int mi = 0; mi < 2; ++mi)
#pragma unroll
                for (int ni = 0; ni < 8; ++ni)
                    acc[mi][ni] = __builtin_amdgcn_mfma_f32_16x16x32_bf16(qa[mi], sv[ni], acc[mi][ni], 0, 0, 0);
        }
        __syncthreads();
    }

    // softmax over j (cols): per (mi, r) row: 8 ni per lane x 16 lanes
#pragma unroll
    for (int mi = 0; mi < 2; ++mi) {
#pragma unroll
        for (int r = 0; r < 4; ++r) {
            float mx = acc[mi][0][r];
#pragma unroll
            for (int ni = 1; ni < 8; ++ni) mx = fmaxf(mx, acc[mi][ni][r]);
            for (int m = 1; m < 16; m <<= 1) mx = fmaxf(mx, __shfl_xor(mx, m));
            float sm = 0.f;
#pragma unroll
            for (int ni = 0; ni < 8; ++ni) {
                float e = __expf(acc[mi][ni][r] - mx);
                acc[mi][ni][r] = e; sm += e;
            }
            for (int m = 1; m < 16; m <<= 1) sm += __shfl_xor(sm, m);
            float inv = 1.f / sm;
#pragma unroll
            for (int ni = 0; ni < 8; ++ni) acc[mi][ni][r] *= inv;
        }
    }

    if (STORE_M) {
        short* Mb = (short*)Mout + (size_t)bh * 16384;
#pragma unroll
        for (int ni = 0; ni < 8; ++ni) {
            int j = ni * 16 + lrow;
            int pj = (j >> 6) * 64 + mf_p64(j & 63);
#pragma unroll
            for (int mi = 0; mi < 2; ++mi)
#pragma unroll
                for (int r = 0; r < 4; ++r) {
                    int i = wave * 32 + mi * 16 + lg * 4 + r;
                    Mb[i * 128 + (pj ^ ((i & 7) << 3))] = (short)f2bf_bits(acc[mi][ni][r]);
                }
        }
    } else {
        __shared__ float cs[16][128];
#pragma unroll
        for (int ni = 0; ni < 8; ++ni) {
            float s = 0.f;
#pragma unroll
            for (int mi = 0; mi < 2; ++mi)
#pragma unroll
                for (int r = 0; r < 4; ++r) s += acc[mi][ni][r];
            cs[wave * 4 + lg][ni * 16 + lrow] = s;
        }
        __syncthreads();
        if (tid < 128) {
            float s = 0.f;
#pragma unroll
            for (int g = 0; g < 16; ++g) s += cs[g][tid];
            m0out[(size_t)b * HWSZ + h * WW + tid] = (s > 0.1f) ? 0.f : 1.f;
        }
    }
}

// ---------------------------------------------------------------- attention apply (MFMA)
// M (MF-j) staged via DMA; V (NCHW, j-contiguous) staged via VALU repack.
__device__ __forceinline__ void stage_rm(short* __restrict__ Xs, const bf16* __restrict__ src,
                                         size_t rstride, int k0, int tid)
{
    const int row = tid & 127;
    const int kh = (tid >> 7) * 32;
    const short* sp = (const short*)src + (size_t)row * rstride + k0 + kh;
    const int swz = (row & 7) << 3;
    short* dst = Xs + row * 64;
    short8v lv[4];
#pragma unroll
    for (int q = 0; q < 4; ++q) lv[q] = *(const short8v*)(sp + q * 8);
#pragma unroll
    for (int g = 0; g < 4; ++g) {
        unsigned short u[8];
#pragma unroll
        for (int r = 0; r < 4; ++r) {
            u[r]     = (unsigned short)lv[g >> 1][(g & 1) * 4 + r];
            u[4 + r] = (unsigned short)lv[2 + (g >> 1)][(g & 1) * 4 + r];
        }
        uint4 wv;
        wv.x = (unsigned)u[0] | ((unsigned)u[1] << 16);
        wv.y = (unsigned)u[2] | ((unsigned)u[3] << 16);
        wv.z = (unsigned)u[4] | ((unsigned)u[5] << 16);
        wv.w = (unsigned)u[6] | ((unsigned)u[7] << 16);
        *(uint4*)(dst + ((kh + g * 8) ^ swz)) = wv;
    }
}

__global__ __launch_bounds__(256) void attn_apply_kernel(
    const bf16* __restrict__ Mbuf, const bf16* __restrict__ v3,
    bf16* __restrict__ outb)
{
    int bh = blockIdx.x; int b = bh >> 7, h = bh & 127;
    int ch0 = blockIdx.y * 128;
    const char* Mb = (const char*)Mbuf + (size_t)bh * 32768;
    const bf16* Vb = v3 + ((size_t)b * CC + ch0) * HWSZ + h * WW;
    bf16* Ob = outb + ((size_t)b * CC + ch0) * HWSZ + h * WW;
    __shared__ __align__(16) short Ms[128 * 64];
    __shared__ __align__(16) short Vs[128 * 64];
    const int tid = threadIdx.x;
    const int lane = tid & 63, wave = tid >> 6;
    const int lrow = lane & 15, lg = lane >> 4;
    const int sA = (lrow & 7) << 3;

    f32x4 acc[2][8];
#pragma unroll
    for (int mi = 0; mi < 2; ++mi)
#pragma unroll
        for (int ni = 0; ni < 8; ++ni) acc[mi][ni] = (f32x4)(0.f);

    for (int kt = 0; kt < 2; ++kt) {
        const int k0 = kt * 64;
        {
            const int lofs = (lane >> 3) * 256 + (lane & 7) * 16 + kt * 128;
#pragma unroll
            for (int q = 0; q < 4; ++q)
                gld16(Mb + (size_t)(wave * 32 + q * 8) * 256 + lofs, (char*)Ms + wave * 4096 + q * 1024);
        }
        stage_rm(Vs, Vb, HWSZ, k0, tid);  // V rows are j-contiguous
        __syncthreads();
#pragma unroll
        for (int kk = 0; kk < 2; ++kk) {
            const int kofs = (kk * 32 + lg * 8) ^ sA;
            short8v ma[2], vv[8];
#pragma unroll
            for (int mi = 0; mi < 2; ++mi)
                ma[mi] = *(const short8v*)&Ms[(wave * 32 + mi * 16 + lrow) * 64 + kofs];
#pragma unroll
            for (int ni = 0; ni < 8; ++ni)
                vv[ni] = *(const short8v*)&Vs[(ni * 16 + lrow) * 64 + kofs];
#pragma unroll
            for (int mi = 0; mi < 2; ++mi)
#pragma unroll
                for (int ni = 0; ni < 8; ++ni)
                    acc[mi][ni] = __builtin_amdgcn_mfma_f32_16x16x32_bf16(ma[mi], vv[ni], acc[mi][ni], 0, 0, 0);
        }
        __syncthreads();
    }

#pragma unroll
    for (int ni = 0; ni < 8; ++ni) {
        const int c = ni * 16 + lrow;
#pragma unroll
        for (int mi = 0; mi < 2; ++mi) {
            const int i0 = wave * 32 + mi * 16 + lg * 4;
            float vals[4] = { acc[mi][ni][0], acc[mi][ni][1], acc[mi][ni][2], acc[mi][ni][3] };
            store4(&Ob[(size_t)c * HWSZ + i0], vals);
        }
    }
}

// ---------------------------------------------------------------- morphology
__global__ void morph_kernel(const float* __restrict__ in, float* __restrict__ out,
                             int Hd, int Wd, int r, float thresh) {
    int idx = blockIdx.x * 256 + threadIdx.x;
    int tot = BB * Hd * Wd;
    if (idx >= tot) return;
    int x = idx % Wd; int y = (idx / Wd) % Hd; int b = idx / (Wd * Hd);
    const float* base = in + (size_t)b * Hd * Wd;
    float s = 0.f;
    for (int dy = -r; dy <= r; ++dy) {
        int yy = y + dy; if (yy < 0 || yy >= Hd) continue;
        for (int dx = -r; dx <= r; ++dx) {
            if (dx * dx + dy * dy > r * r) continue;
            int xx = x + dx; if (xx < 0 || xx >= Wd) continue;
            s += base[yy * Wd + xx];
        }
    }
    out[idx] = (s > thresh) ? 1.f : 0.f;
}

__global__ void pad3_kernel(const float* __restrict__ in, float* __restrict__ out) {
    int idx = blockIdx.x * 256 + threadIdx.x;
    int tot = BB * 134 * 134; if (idx >= tot) return;
    int x = idx % 134; int y = (idx / 134) % 134; int b = idx / (134 * 134);
    float v = 0.f;
    int xs = x - 3, ys = y - 3;
    if (xs >= 0 && xs < 128 && ys >= 0 && ys < 128)
        v = in[((size_t)b * 128 + ys) * 128 + xs];
    out[idx] = v;
}

__global__ void vfinal_kernel(const float* __restrict__ in, float* __restrict__ V) {
    int idx = blockIdx.x * 256 + threadIdx.x; // B*HWSZ
    if (idx >= BB * HWSZ) return;
    int x = idx & 127; int y = (idx >> 7) & 127; int b = idx >> 14;
    V[idx] = 1.f - in[((size_t)b * 134 + y + 3) * 134 + (x + 3)];
}

// ---------------------------------------------------------------- launch
extern "C" void kernel_launch(void* const* d_in, const int* in_sizes, int n_in,
                              void* d_out, int out_size, void* d_ws, size_t ws_size,
                              hipStream_t stream) {
    const float* x_p   = (const float*)d_in[0];
    const float* x_c   = (const float*)d_in[1];
    const float* pa_w1 = (const float*)d_in[2];
    const float* pa_b1 = (const float*)d_in[3];
    const float* pa_w2 = (const float*)d_in[4];
    const float* pa_b2 = (const float*)d_in[5];
    const float* pa_wc = (const float*)d_in[6];
    const float* pa_bc = (const float*)d_in[7];
    const float* ca_aw1 = (const float*)d_in[8];
    const float* ca_ab1 = (const float*)d_in[9];
    const float* ca_aw2 = (const float*)d_in[10];
    const float* ca_ab2 = (const float*)d_in[11];
    const float* ca_mw1 = (const float*)d_in[12];
    const float* ca_mb1 = (const float*)d_in[13];
    const float* ca_mw2 = (const float*)d_in[14];
    const float* ca_mb2 = (const float*)d_in[15];
    const float* b1_w  = (const float*)d_in[16];
    const float* b1_b  = (const float*)d_in[17];
    const float* b2_w  = (const float*)d_in[18];
    const float* b2_b  = (const float*)d_in[19];
    const float* b3_w  = (const float*)d_in[20];
    const float* b3_b  = (const float*)d_in[21];
    const float* fus_w = (const float*)d_in[22];
    const float* fus_b = (const float*)d_in[23];
    float* out = (float*)d_out;

    char* wsb = (char*)d_ws;
    bf16* A  = (bf16*)wsb;                    // NTOT bf16 (64 MiB)
    bf16* Bb = (bf16*)(wsb + NTOT * 2);       // NTOT bf16 (64 MiB)
    float* smalls = (float*)(wsb + NTOT * 4);
    float* avgv = smalls;                     // 2048
    float* maxv = smalls + 2048;              // 2048
    float* gate = smalls + 4096;              // 2048
    float* mph0 = smalls + 6144;              // 143648
    float* mph1 = mph0 + 143648;              // 143648
    float* Vfin = mph1 + 143648;              // 131072
    short* Wprep = (short*)(wsb + NTOT * 4 + 1703936);  // 2.25 MiB
    const short* Wp_paw1 = Wprep + 0;
    const short* Wp_paw2 = Wprep + 131072;
    const short* Wp_pawc = Wprep + 262144;
    const short* Wp_b1   = Wprep + 524288;
    const short* Wp_b2   = Wprep + 655360;
    const short* Wp_b3   = Wprep + 786432;
    const short* Wp_fus  = Wprep + 917504;
    bf16* D1 = (bf16*)d_out;                  // NTOT bf16 (d_out scratch)
    bf16* D2 = D1 + NTOT;                     // NTOT bf16
    bf16* Mbuf = A;                           // 33.5 MB, lives in A after bufp chain

    dim3 cgrid(HWSZ / 128, 2, BB);            // (128, 2, 8)
    const int TPB = 256;

    // --- weight prep + CA gate (independent of PA chain) ---
    prep_w_kernel<<<2304, TPB, 0, stream>>>(pa_w1, pa_w2, pa_wc, b1_w, b2_w, b3_w, fus_w, Wprep);
    ca_reduce_kernel<<<BB * CC, TPB, 0, stream>>>(x_c, avgv, maxv);
    ca_mlp_kernel<<<BB, TPB, 0, stream>>>(avgv, maxv, ca_aw1, ca_ab1, ca_aw2, ca_ab2,
                                          ca_mw1, ca_mb1, ca_mw2, ca_mb2, gate);

    // --- PALayer (all MF) ---
    pool3_mf_kernel<<<16384, TPB, 0, stream>>>(x_p, A, Bb);           // y1->A, y2->Bb (MF)
    conv_mf_kernel<EPI_RELU, false, bf16>
        <<<cgrid, TPB, 0, stream>>>(D1, A, nullptr, Wp_paw1, pa_b1, nullptr);   // z1->D1
    conv_mf_kernel<EPI_ADDAUX, false, bf16>
        <<<cgrid, TPB, 0, stream>>>(D2, D1, nullptr, Wp_paw2, pa_b2, A);        // u=conv+y1 ->D2
    conv_mf_kernel<EPI_RELU, false, bf16>
        <<<cgrid, TPB, 0, stream>>>(A, Bb, nullptr, Wp_paw1, pa_b1, nullptr);   // z2->A
    conv_mf_kernel<EPI_ADDAUX, false, bf16>
        <<<cgrid, TPB, 0, stream>>>(D1, A, nullptr, Wp_paw2, pa_b2, Bb);        // v=conv+y2 ->D1
    conv_mf_kernel<EPI_SIGMUL, true, float>
        <<<cgrid, TPB, 0, stream>>>(A, D2, D1, Wp_pawc, pa_bc, x_p);            // buffer_p->A

    // --- Q/S projections ---
    conv_mf_kernel<EPI_NONE, false, bf16>
        <<<cgrid, TPB, 0, stream>>>(Bb, A, nullptr, Wp_b1, b1_b, nullptr);      // Q1->Bb
    conv_mf_kernel<EPI_NONE, false, bf16>
        <<<cgrid, TPB, 0, stream>>>(D1, A, nullptr, Wp_b2, b2_b, nullptr);      // S2->D1
    xcs_prep_kernel<<<16384, TPB, 0, stream>>>(x_c, gate, D2);                  // xcs->D2 (MF)
    conv_mf_kernel<EPI_NONE, false, bf16>
        <<<cgrid, TPB, 0, stream>>>(A, D2, nullptr, Wp_b1, b1_b, nullptr);      // Q2->A

    // --- attention 1: M_p_to_c colsum -> m0 ---
    attn_kernel<false><<<BB * HH, TPB, 0, stream>>>(A, D1, nullptr, mph0);      // (Q2, S2)

    conv_mf_kernel<EPI_NONE, false, bf16>
        <<<cgrid, TPB, 0, stream>>>(D1, D2, nullptr, Wp_b2, b2_b, nullptr);     // S1->D1

    // --- attention 2: M_c_to_p -> Mbuf (in A) ---
    attn_kernel<true><<<BB * HH, TPB, 0, stream>>>(Bb, D1, Mbuf, nullptr);      // (Q1, S1)

    // --- v3 (NCHW out for attn_apply) ---
    conv1x1_kernel<EPI_NONE, false, false, float, float, bf16>
        <<<cgrid, TPB, 0, stream>>>(D2, x_c, nullptr, Wp_b3, b3_b,
                                    nullptr, nullptr, 0);                       // v3->D2

    // --- morphology (tiny) ---
    morph_kernel<<<512, TPB, 0, stream>>>(mph0, mph1, 128, 128, 2, 12.5f);
    morph_kernel<<<512, TPB, 0, stream>>>(mph1, mph0, 128, 128, 2, 0.5f);
    morph_kernel<<<512, TPB, 0, stream>>>(mph0, mph1, 128, 128, 1, 0.5f);
    morph_kernel<<<512, TPB, 0, stream>>>(mph1, mph0, 128, 128, 1, 4.5f);
    pad3_kernel<<<562, TPB, 0, stream>>>(mph0, mph1);
    morph_kernel<<<562, TPB, 0, stream>>>(mph1, mph0, 134, 134, 3, 0.5f);
    morph_kernel<<<562, TPB, 0, stream>>>(mph0, mph1, 134, 134, 3, 28.5f);
    vfinal_kernel<<<512, TPB, 0, stream>>>(mph1, Vfin);

    // --- attend + fusion ---
    attn_apply_kernel<<<dim3(BB * HH, 2), TPB, 0, stream>>>(Mbuf, D2, Bb);      // buf->Bb (NCHW)
    conv1x1_kernel<EPI_NONE, true, true, bf16, float, float>
        <<<cgrid, TPB, 0, stream>>>(out, Bb, x_p, Wp_fus, fus_b,
                                    Vfin, fus_w + 512, 513);                    // final -> d_out fp32
}